// Round 3
// baseline (289.545 us; speedup 1.0000x reference)
//
#include <hip/hip_runtime.h>
#include <math.h>

// DeepMMD, round 5: joint symmetric 8192x8192 pass, 128x128 tiles (2080 blocks).
//  - pair_kernel now 512 threads / 8 waves per block: same 64KiB LDS -> still
//    2 blocks/CU, but 4 waves/SIMD (was 2) for latency hiding. Per-thread work
//    halved in every phase; arithmetic identical to round 4.
//  - org-space dot: fp16 hi/lo split (3 products) on v_mfma_f32_32x32x16_f16
//  - feature distance: exact fp32 SSD, packed float2 (precision-critical)
//  - phase A: register-prefetch of next K-block across a raw s_barrier
//  - reductions: row/col sums -> fp32 atomics on D8[8192]; S* fp64 atomics

#define N_S 4096
#define LOG2E 1.4426950408889634

typedef _Float16 v8h __attribute__((ext_vector_type(8)));
typedef float v16f __attribute__((ext_vector_type(16)));
typedef float v2f __attribute__((ext_vector_type(2)));

union U16 { uint4 u; v8h h; };

// ---------------- MLP (fp64 internals), 8-way k-split ----------------
__global__ __launch_bounds__(256)
void mlp_kernel(const float* __restrict__ X, const float* __restrict__ Y,
                const float* __restrict__ W1, const float* __restrict__ b1,
                const float* __restrict__ W2, const float* __restrict__ b2,
                const float* __restrict__ W3, const float* __restrict__ b3,
                const float* __restrict__ W4, const float* __restrict__ b4,
                const float* __restrict__ sq,
                float* __restrict__ featsT, float* __restrict__ wOrg)
{
    __shared__ double sW1[8 * 330];
    __shared__ double sW2[100], sW3[100], sW4[500];
    __shared__ double sb1[10], sb2[10], sb3[10], sb4[50];
    int tid = threadIdx.x;
    {
        int kg = tid >> 5, kl = tid & 31;
#pragma unroll
        for (int j = 0; j < 10; ++j)
            sW1[kg * 330 + kl * 10 + j] = (double)W1[tid * 10 + j];
    }
    for (int i = tid; i < 100; i += 256) { sW2[i] = (double)W2[i]; sW3[i] = (double)W3[i]; }
    for (int i = tid; i < 500; i += 256) sW4[i] = (double)W4[i];
    if (tid < 10) { sb1[tid] = (double)b1[tid]; sb2[tid] = (double)b2[tid]; sb3[tid] = (double)b3[tid]; }
    if (tid < 50) sb4[tid] = (double)b4[tid];
    __syncthreads();

    int gt = blockIdx.x * 256 + tid;
    int r = gt >> 3, g = gt & 7;
    const float* xr = (r < N_S) ? (X + (size_t)r * 256) : (Y + (size_t)(r - N_S) * 256);
    const float* xrg = xr + g * 32;
    const double* w1g = sW1 + g * 330;

    double z[10];
#pragma unroll
    for (int j = 0; j < 10; ++j) z[j] = 0.0;
    double nrm = 0.0;
    for (int k4 = 0; k4 < 32; k4 += 4) {
        float4 xv4 = *(const float4*)(xrg + k4);
        double xv[4] = {(double)xv4.x, (double)xv4.y, (double)xv4.z, (double)xv4.w};
#pragma unroll
        for (int u = 0; u < 4; ++u) {
            nrm += xv[u] * xv[u];
#pragma unroll
            for (int j = 0; j < 10; ++j) z[j] += xv[u] * w1g[(k4 + u) * 10 + j];
        }
    }
#pragma unroll
    for (int off = 1; off < 8; off <<= 1) {
        nrm += __shfl_xor(nrm, off);
#pragma unroll
        for (int j = 0; j < 10; ++j) z[j] += __shfl_xor(z[j], off);
    }
#pragma unroll
    for (int j = 0; j < 10; ++j) z[j] += sb1[j];
#pragma unroll
    for (int j = 0; j < 10; ++j) z[j] = fmax(z[j], 0.0) + log1p(exp(-fabs(z[j])));

    double z2[10];
#pragma unroll
    for (int j = 0; j < 10; ++j) z2[j] = sb2[j];
#pragma unroll
    for (int k = 0; k < 10; ++k)
#pragma unroll
        for (int j = 0; j < 10; ++j) z2[j] += z[k] * sW2[k * 10 + j];
#pragma unroll
    for (int j = 0; j < 10; ++j) z2[j] = fmax(z2[j], 0.0) + log1p(exp(-fabs(z2[j])));

    double z3[10];
#pragma unroll
    for (int j = 0; j < 10; ++j) z3[j] = sb3[j];
#pragma unroll
    for (int k = 0; k < 10; ++k)
#pragma unroll
        for (int j = 0; j < 10; ++j) z3[j] += z2[k] * sW3[k * 10 + j];
#pragma unroll
    for (int j = 0; j < 10; ++j) z3[j] = fmax(z3[j], 0.0) + log1p(exp(-fabs(z3[j])));

    for (int j = 0; j < 50; ++j) {
        double f = sb4[j];
#pragma unroll
        for (int k = 0; k < 10; ++k) f += z3[k] * sW4[k * 50 + j];
        if ((j & 7) == g) featsT[(size_t)j * 8192 + r] = (float)f;
    }
    if (g == 2) featsT[(size_t)50 * 8192 + r] = 0.0f;
    if (g == 3) featsT[(size_t)51 * 8192 + r] = 0.0f;

    if (g == 0) {
        double sqv = (double)sq[0];
        double co = LOG2E / (sqv * sqv);
        wOrg[r] = (float)exp2(-nrm * co);
    }
}

// ---------------- helpers ----------------
__device__ __forceinline__ v8h ldfrag(const uint4* buf, int s, int g) {
    U16 t; t.u = buf[s * 8 + (g ^ (s & 7))];
    return t.h;
}

__device__ __forceinline__ void cvt_split(float4 f0, float4 f1, uint4* hi, uint4* lo) {
    U16 H, L;
    float fv[8] = {f0.x, f0.y, f0.z, f0.w, f1.x, f1.y, f1.z, f1.w};
#pragma unroll
    for (int u = 0; u < 8; ++u) {
        _Float16 h = (_Float16)fv[u];
        H.h[u] = h;
        L.h[u] = (_Float16)(fv[u] - (float)h);
    }
    *hi = H.u; *lo = L.u;
}

// ---------------- joint pairwise pass (512 threads / 8 waves) ----------------
__global__ __launch_bounds__(512, 4)
void pair_kernel(const float* __restrict__ X, const float* __restrict__ Y,
                 const float* __restrict__ featsT, const float* __restrict__ wOrg,
                 const float* __restrict__ ep, const float* __restrict__ sq,
                 const float* __restrict__ sph,
                 float* __restrict__ D8, double* __restrict__ S)
{
    // LDS union: phase F: FA[50][132] (26400) + FB[50][128] swizzled (25600)
    //            phase A: Ahi/Alo/Bhi/Blo uint4[1024] each = 65536
    //            epilogue: E2[128][128] f32 = 65536; dred 16 f64 (overlaid)
    __shared__ __align__(16) char smem[65536];

    int tid = threadIdx.x;
    int lane = tid & 63, w = tid >> 6;
    int wr2 = w >> 2, wc4 = w & 3;          // MFMA wave grid: 2 row-halves x 4 col-quarters
    int tx = tid & 31, ty = tid >> 5;       // phase-F grid: 32 col-groups x 16 row-groups

    // upper-triangle tile decode
    int L = blockIdx.x, it = 0, span = 64;
    while (L >= span) { L -= span; --span; ++it; }
    int jt = it + L;

    bool sameHalf = (jt < 32) || (it >= 32);
    bool isDiag = (it == jt);
    bool isTrace = (jt == it + 32);
    int region = (jt < 32) ? 0 : ((it >= 32) ? 1 : 2);
    float sgn = sameHalf ? 1.0f : -1.0f;
    int i0 = it * 128, j0 = jt * 128;
    const float* aorg = (it < 32) ? X + (size_t)i0 * 256 : Y + (size_t)(i0 - N_S) * 256;
    const float* borg = (jt < 32) ? X + (size_t)j0 * 256 : Y + (size_t)(j0 - N_S) * 256;

    double epd = (double)ep[0];
    double eps = 1.0 / (1.0 + exp(-epd));
    double sqv = (double)sq[0], spv = (double)sph[0];
    float cf = (float)(LOG2E / (spv * spv));
    float twoco = (float)(2.0 * LOG2E / (sqv * sqv));
    float epsv = (float)eps, ome = (float)(1.0 - eps);

    // prefetch buffer for phase-A staging (one K-block: 8 float4 per thread)
    float4 R[8];
    auto loadregs = [&](int kb) {
#pragma unroll
        for (int step = 0; step < 2; ++step) {
            int rr = step * 64 + (tid >> 3), g8 = tid & 7;
            const float* pa = aorg + (size_t)rr * 256 + kb + g8 * 8;
            const float* pb = borg + (size_t)rr * 256 + kb + g8 * 8;
            R[step * 4 + 0] = *(const float4*)pa;
            R[step * 4 + 1] = *(const float4*)(pa + 4);
            R[step * 4 + 2] = *(const float4*)pb;
            R[step * 4 + 3] = *(const float4*)(pb + 4);
        }
    };

    // ---- phase F: exact fp32 feature distances (8x4 per thread, packed f32) ----
    float* FA = (float*)smem;
    float* FB = (float*)(smem + 26400);
    for (int idx = tid; idx < 1600; idx += 512) {    // 50 rows x 32 chunks
        int k = idx >> 5, c = idx & 31, cg = c * 4;
        *(float4*)&FA[k * 132 + cg] = *(const float4*)&featsT[(size_t)k * 8192 + i0 + cg];
        int cs = (c ^ (c >> 4)) * 4;                 // chunk swizzle
        *(float4*)&FB[k * 128 + cs] = *(const float4*)&featsT[(size_t)k * 8192 + j0 + cg];
    }
    loadregs(0);       // org K-block 0 in flight across all of phase F
    __syncthreads();

    v2f da2[8][2];
#pragma unroll
    for (int i = 0; i < 8; ++i)
#pragma unroll
        for (int j = 0; j < 2; ++j) { da2[i][j][0] = 0.0f; da2[i][j][1] = 0.0f; }

    int r0 = ty * 8, c0f = tx * 4;
    int fboff = (tx ^ (tx >> 4)) * 4;
    for (int k = 0; k < 50; ++k) {
        float4 a0 = *(const float4*)&FA[k * 132 + r0];
        float4 a1 = *(const float4*)&FA[k * 132 + r0 + 4];
        float4 b0 = *(const float4*)&FB[k * 128 + fboff];
        float av[8] = {a0.x, a0.y, a0.z, a0.w, a1.x, a1.y, a1.z, a1.w};
        v2f bv[2];
        bv[0][0] = b0.x; bv[0][1] = b0.y; bv[1][0] = b0.z; bv[1][1] = b0.w;
#pragma unroll
        for (int i = 0; i < 8; ++i) {
            v2f ai; ai[0] = av[i]; ai[1] = av[i];
#pragma unroll
            for (int j = 0; j < 2; ++j) {
                v2f t = ai - bv[j];
                da2[i][j] += t * t;
            }
        }
    }
#pragma unroll
    for (int i = 0; i < 8; ++i)
#pragma unroll
        for (int j = 0; j < 2; ++j) {
            da2[i][j][0] = exp2f(-da2[i][j][0] * cf);
            da2[i][j][1] = exp2f(-da2[i][j][1] * cf);
        }
    __syncthreads();   // FA/FB dead

    // ---- phase A: fp16-split MFMA org dot, reg-prefetch pipeline ----
    uint4* Ahi = (uint4*)smem;
    uint4* Alo = Ahi + 1024;
    uint4* Bhi = Ahi + 2048;
    uint4* Blo = Ahi + 3072;

    v16f acc0{}, acc1{};
    int rs0 = wr2 * 64 + (lane & 31), rs1 = rs0 + 32;
    int cs = wc4 * 32 + (lane & 31);

    for (int kb = 0; kb < 256; kb += 64) {
#pragma unroll
        for (int step = 0; step < 2; ++step) {
            int rr = step * 64 + (tid >> 3), g8 = tid & 7;
            int pg = rr * 8 + (g8 ^ (rr & 7));          // XOR swizzle, conflict-free b128
            uint4 hi, lo;
            cvt_split(R[step * 4 + 0], R[step * 4 + 1], &hi, &lo);
            Ahi[pg] = hi; Alo[pg] = lo;
            cvt_split(R[step * 4 + 2], R[step * 4 + 3], &hi, &lo);
            Bhi[pg] = hi; Blo[pg] = lo;
        }
        __syncthreads();            // vmcnt naturally 0 here (R consumed); free drain
        if (kb < 192) loadregs(kb + 64);    // next K-block in flight across MFMA phase
        __builtin_amdgcn_s_setprio(1);
#pragma unroll
        for (int ks = 0; ks < 4; ++ks) {
            int g = ks * 2 + (lane >> 5);
            v8h ah0 = ldfrag(Ahi, rs0, g), ah1 = ldfrag(Ahi, rs1, g);
            v8h al0 = ldfrag(Alo, rs0, g), al1 = ldfrag(Alo, rs1, g);
            v8h bh = ldfrag(Bhi, cs, g), bl = ldfrag(Blo, cs, g);
            acc0 = __builtin_amdgcn_mfma_f32_32x32x16_f16(al0, bh, acc0, 0, 0, 0);
            acc0 = __builtin_amdgcn_mfma_f32_32x32x16_f16(ah0, bl, acc0, 0, 0, 0);
            acc0 = __builtin_amdgcn_mfma_f32_32x32x16_f16(ah0, bh, acc0, 0, 0, 0);
            acc1 = __builtin_amdgcn_mfma_f32_32x32x16_f16(al1, bh, acc1, 0, 0, 0);
            acc1 = __builtin_amdgcn_mfma_f32_32x32x16_f16(ah1, bl, acc1, 0, 0, 0);
            acc1 = __builtin_amdgcn_mfma_f32_32x32x16_f16(ah1, bh, acc1, 0, 0, 0);
        }
        __builtin_amdgcn_s_setprio(0);
        // raw barrier: all ds_reads already consumed by MFMAs (lgkm drained),
        // no ds_writes pending; keeps prefetch loads in flight (a __syncthreads
        // here would vmcnt(0)-drain them).
        __builtin_amdgcn_sched_barrier(0);
        __builtin_amdgcn_s_barrier();
        __builtin_amdgcn_sched_barrier(0);
    }

    // ---- epilogue: single full-tile pass, all 8 waves ----
    float* E2 = (float*)smem;

    // write e2 (thread-tile layout) into full 128x128 LDS tile
#pragma unroll
    for (int i = 0; i < 8; ++i) {
        float4 v0 = make_float4(da2[i][0][0], da2[i][0][1], da2[i][1][0], da2[i][1][1]);
        *(float4*)&E2[(r0 + i) * 128 + c0f] = v0;
    }
    __syncthreads();

    // each wave evaluates its own 2 accs in MFMA C-layout
    double bsum = 0.0, trsum = 0.0;
    float colacc = 0.0f;
    int cl = wc4 * 32 + (lane & 31);
    float wb = wOrg[j0 + cl];

    auto evalacc = [&](const v16f& a, int rbase) {
        float4 wa4[4];
#pragma unroll
        for (int q = 0; q < 4; ++q)
            wa4[q] = *(const float4*)&wOrg[i0 + rbase + 4 * (lane >> 5) + 8 * q];
#pragma unroll
        for (int reg = 0; reg < 16; ++reg) {
            int rl = rbase + 4 * (lane >> 5) + (reg & 3) + 8 * (reg >> 2);
            float wa = ((const float*)&wa4[reg >> 2])[reg & 3];
            float e2v = E2[rl * 128 + cl];
            float kv = wa * wb * exp2f(a[reg] * twoco) * (ome * e2v + epsv);
            if (isDiag && rl == cl) kv = 0.0f;
            if (isTrace && cl == rl) trsum += (double)kv;
            bsum += (double)kv;
            colacc += kv;
            E2[rl * 128 + cl] = kv;
        }
    };
    evalacc(acc0, wr2 * 64);
    evalacc(acc1, wr2 * 64 + 32);
    __syncthreads();

    // row sums: 4 threads per row, rotated start to spread banks
    {
        int row = tid >> 2, q = tid & 3;
        float s = 0.0f;
#pragma unroll
        for (int c = 0; c < 8; ++c) {
            int cc = (c + row) & 7;
            float4 v = *(const float4*)&E2[row * 128 + q * 32 + cc * 4];
            s += v.x + v.y + v.z + v.w;
        }
        s += __shfl_xor(s, 1);
        s += __shfl_xor(s, 2);
        if (q == 0) atomicAdd(&D8[i0 + row], sgn * s);
    }

    // column sums (skip for diagonal tiles: rows already cover both triangles)
    if (!isDiag) {
        atomicAdd(&D8[j0 + cl], sgn * colacc);
    }

    // block reduce bsum (+ trace): wave shuffle then 8-way LDS
#pragma unroll
    for (int off = 32; off > 0; off >>= 1) bsum += __shfl_down(bsum, off);
    if (isTrace) {
#pragma unroll
        for (int off = 32; off > 0; off >>= 1) trsum += __shfl_down(trsum, off);
    }
    __syncthreads();               // E2 reads done; reuse smem as dred
    double* dred = (double*)smem;
    if (lane == 0) { dred[w] = bsum; dred[8 + w] = trsum; }
    __syncthreads();
    if (tid == 0) {
        double wgt = (sameHalf && !isDiag) ? 2.0 : 1.0;
        double t0 = 0.0, t1 = 0.0;
#pragma unroll
        for (int q = 0; q < 8; ++q) { t0 += dred[q]; t1 += dred[8 + q]; }
        atomicAdd(&S[region], wgt * t0);
        if (isTrace) atomicAdd(&S[3], t1);
    }
}

// ---------------- final scalar assembly ----------------
__global__ __launch_bounds__(256)
void final_kernel(const float* __restrict__ D8, const double* __restrict__ S,
                  float* __restrict__ out)
{
    __shared__ double buf[512];
    int tid = threadIdx.x;
    double sD = 0, sD2 = 0;
    for (int i = tid; i < 4096; i += 256) {
        double d = (double)D8[i] + (double)D8[i + 4096];
        sD += d; sD2 += d * d;
    }
    buf[tid] = sD; buf[256 + tid] = sD2;
    __syncthreads();
    for (int s = 128; s > 0; s >>= 1) {
        if (tid < s) { buf[tid] += buf[tid + s]; buf[256 + tid] += buf[256 + tid + s]; }
        __syncthreads();
    }
    if (tid == 0) {
        double n = (double)N_S, D = n * (n - 1.0);
        double xx = S[0] / D, yy = S[1] / D, xy = (S[2] - S[3]) / D;
        double mmd2 = xx - 2.0 * xy + yy;
        double sumd = buf[0], sumd2 = buf[256];
        double sumh = 2.0 * n + sumd;                    // hs_i = 2 + delta_i
        double sumhs2 = 4.0 * n + 4.0 * sumd + sumd2;
        double n3 = n * n * n, n4 = n3 * n;
        double var = 4.0 / n3 * sumhs2 - 4.0 / n4 * sumh * sumh + 1e-8;
        out[0] = (float)mmd2;
        out[1] = (float)var;
    }
}

extern "C" void kernel_launch(void* const* d_in, const int* in_sizes, int n_in,
                              void* d_out, int out_size, void* d_ws, size_t ws_size,
                              hipStream_t stream)
{
    const float* X   = (const float*)d_in[0];
    const float* Y   = (const float*)d_in[1];
    const float* W1  = (const float*)d_in[2];
    const float* b1  = (const float*)d_in[3];
    const float* W2  = (const float*)d_in[4];
    const float* b2  = (const float*)d_in[5];
    const float* W3  = (const float*)d_in[6];
    const float* b3  = (const float*)d_in[7];
    const float* W4  = (const float*)d_in[8];
    const float* b4  = (const float*)d_in[9];
    const float* ep  = (const float*)d_in[10];
    const float* sq  = (const float*)d_in[11];
    const float* sph = (const float*)d_in[12];
    float* out = (float*)d_out;

    char* ws = (char*)d_ws;
    float*  featsT = (float*)ws;                      // 52*8192*4 = 1703936
    float*  wOrg   = (float*)(ws + 1703936);          // 32768
    float*  D8     = (float*)(ws + 1736704);          // 32768
    double* S      = (double*)(ws + 1769472);         // 32 (Sxx, Syy, Sxy, trace)

    hipMemsetAsync(D8, 0, 32768 + 32, stream);

    mlp_kernel<<<256, 256, 0, stream>>>(X, Y, W1, b1, W2, b2, W3, b3, W4, b4,
                                        sq, featsT, wOrg);

    pair_kernel<<<2080, 512, 0, stream>>>(X, Y, featsT, wOrg, ep, sq, sph, D8, S);

    final_kernel<<<1, 256, 0, stream>>>(D8, S, out);
}

// Round 4
// 228.483 us; speedup vs baseline: 1.2672x; 1.2672x over previous
//
#include <hip/hip_runtime.h>
#include <math.h>

// DeepMMD, round 6: joint symmetric 8192x8192 pass, 128x128 tiles (2080 blocks).
//  - feature distance now via MFMA norm-trick: d = na + nb - 2*dot, dot on the
//    same fp16 hi/lo 3-product v_mfma_f32_32x32x16_f16 path as the org dot
//    (features staged from row-major featsR[8192][64], zero-padded 52->64).
//    Safe because sigma_phi^2=0.005 makes every smooth term exp(-d/0.005)~0
//    for d = O(1)+; max(d,0) clamp replicated from reference.
//  - phase F (exact fp32 SSD) deleted -> ~halves the VALU stream (r4/r5
//    invariance experiment showed VALU-instruction-throughput-bound).
//  - epilogue: e2 computed in-register; E2 LDS tile only for row sums.
//  - reductions: row/col sums -> fp32 atomics on D8[8192]; S* fp64 atomics.

#define N_S 4096
#define LOG2E 1.4426950408889634

typedef _Float16 v8h __attribute__((ext_vector_type(8)));
typedef float v16f __attribute__((ext_vector_type(16)));

union U16 { uint4 u; v8h h; };

// ---------------- MLP (fp64 internals), 8-way k-split ----------------
// -> featsR[8192][64] fp32 row-major (cols 50..63 zero), normF[8192], wOrg[8192]
__global__ __launch_bounds__(256)
void mlp_kernel(const float* __restrict__ X, const float* __restrict__ Y,
                const float* __restrict__ W1, const float* __restrict__ b1,
                const float* __restrict__ W2, const float* __restrict__ b2,
                const float* __restrict__ W3, const float* __restrict__ b3,
                const float* __restrict__ W4, const float* __restrict__ b4,
                const float* __restrict__ sq,
                float* __restrict__ featsR, float* __restrict__ normF,
                float* __restrict__ wOrg)
{
    __shared__ double sW1[8 * 330];
    __shared__ double sW2[100], sW3[100], sW4[500];
    __shared__ double sb1[10], sb2[10], sb3[10], sb4[50];
    int tid = threadIdx.x;
    {
        int kg = tid >> 5, kl = tid & 31;
#pragma unroll
        for (int j = 0; j < 10; ++j)
            sW1[kg * 330 + kl * 10 + j] = (double)W1[tid * 10 + j];
    }
    for (int i = tid; i < 100; i += 256) { sW2[i] = (double)W2[i]; sW3[i] = (double)W3[i]; }
    for (int i = tid; i < 500; i += 256) sW4[i] = (double)W4[i];
    if (tid < 10) { sb1[tid] = (double)b1[tid]; sb2[tid] = (double)b2[tid]; sb3[tid] = (double)b3[tid]; }
    if (tid < 50) sb4[tid] = (double)b4[tid];
    __syncthreads();

    int gt = blockIdx.x * 256 + tid;
    int r = gt >> 3, g = gt & 7;
    const float* xr = (r < N_S) ? (X + (size_t)r * 256) : (Y + (size_t)(r - N_S) * 256);
    const float* xrg = xr + g * 32;
    const double* w1g = sW1 + g * 330;

    double z[10];
#pragma unroll
    for (int j = 0; j < 10; ++j) z[j] = 0.0;
    double nrm = 0.0;
    for (int k4 = 0; k4 < 32; k4 += 4) {
        float4 xv4 = *(const float4*)(xrg + k4);
        double xv[4] = {(double)xv4.x, (double)xv4.y, (double)xv4.z, (double)xv4.w};
#pragma unroll
        for (int u = 0; u < 4; ++u) {
            nrm += xv[u] * xv[u];
#pragma unroll
            for (int j = 0; j < 10; ++j) z[j] += xv[u] * w1g[(k4 + u) * 10 + j];
        }
    }
#pragma unroll
    for (int off = 1; off < 8; off <<= 1) {
        nrm += __shfl_xor(nrm, off);
#pragma unroll
        for (int j = 0; j < 10; ++j) z[j] += __shfl_xor(z[j], off);
    }
#pragma unroll
    for (int j = 0; j < 10; ++j) z[j] += sb1[j];
#pragma unroll
    for (int j = 0; j < 10; ++j) z[j] = fmax(z[j], 0.0) + log1p(exp(-fabs(z[j])));

    double z2[10];
#pragma unroll
    for (int j = 0; j < 10; ++j) z2[j] = sb2[j];
#pragma unroll
    for (int k = 0; k < 10; ++k)
#pragma unroll
        for (int j = 0; j < 10; ++j) z2[j] += z[k] * sW2[k * 10 + j];
#pragma unroll
    for (int j = 0; j < 10; ++j) z2[j] = fmax(z2[j], 0.0) + log1p(exp(-fabs(z2[j])));

    double z3[10];
#pragma unroll
    for (int j = 0; j < 10; ++j) z3[j] = sb3[j];
#pragma unroll
    for (int k = 0; k < 10; ++k)
#pragma unroll
        for (int j = 0; j < 10; ++j) z3[j] += z2[k] * sW3[k * 10 + j];
#pragma unroll
    for (int j = 0; j < 10; ++j) z3[j] = fmax(z3[j], 0.0) + log1p(exp(-fabs(z3[j])));

    // all 8 lanes of a group compute identical f; each writes its j-share.
    // nf accumulated redundantly (identical fp64 on all lanes).
    double nf = 0.0;
    for (int j = 0; j < 50; ++j) {
        double f = sb4[j];
#pragma unroll
        for (int k = 0; k < 10; ++k) f += z3[k] * sW4[k * 50 + j];
        nf += f * f;
        if ((j & 7) == g) featsR[(size_t)r * 64 + j] = (float)f;
    }
    // zero pad cols 50..63
    featsR[(size_t)r * 64 + 50 + g] = 0.0f;
    if (g < 6) featsR[(size_t)r * 64 + 58 + g] = 0.0f;

    if (g == 0) {
        double sqv = (double)sq[0];
        double co = LOG2E / (sqv * sqv);
        wOrg[r] = (float)exp2(-nrm * co);
    }
    if (g == 1) normF[r] = (float)nf;
}

// ---------------- helpers ----------------
__device__ __forceinline__ v8h ldfrag(const uint4* buf, int s, int g) {
    U16 t; t.u = buf[s * 8 + (g ^ (s & 7))];
    return t.h;
}

__device__ __forceinline__ void cvt_split(float4 f0, float4 f1, uint4* hi, uint4* lo) {
    U16 H, L;
    float fv[8] = {f0.x, f0.y, f0.z, f0.w, f1.x, f1.y, f1.z, f1.w};
#pragma unroll
    for (int u = 0; u < 8; ++u) {
        _Float16 h = (_Float16)fv[u];
        H.h[u] = h;
        L.h[u] = (_Float16)(fv[u] - (float)h);
    }
    *hi = H.u; *lo = L.u;
}

// ---------------- joint pairwise pass (512 threads / 8 waves) ----------------
__global__ __launch_bounds__(512, 2)
void pair_kernel(const float* __restrict__ X, const float* __restrict__ Y,
                 const float* __restrict__ featsR, const float* __restrict__ normF,
                 const float* __restrict__ wOrg,
                 const float* __restrict__ ep, const float* __restrict__ sq,
                 const float* __restrict__ sph,
                 float* __restrict__ D8, double* __restrict__ S)
{
    // LDS union: staging Ahi/Alo/Bhi/Blo uint4[1024] each = 65536
    //            epilogue: E2[128][128] f32 = 65536; dred 16 f64 (overlaid)
    __shared__ __align__(16) char smem[65536];

    int tid = threadIdx.x;
    int lane = tid & 63, w = tid >> 6;
    int wr2 = w >> 2, wc4 = w & 3;          // wave grid: 2 row-halves x 4 col-quarters

    // upper-triangle tile decode
    int L = blockIdx.x, it = 0, span = 64;
    while (L >= span) { L -= span; --span; ++it; }
    int jt = it + L;

    bool sameHalf = (jt < 32) || (it >= 32);
    bool isDiag = (it == jt);
    bool isTrace = (jt == it + 32);
    int region = (jt < 32) ? 0 : ((it >= 32) ? 1 : 2);
    float sgn = sameHalf ? 1.0f : -1.0f;
    int i0 = it * 128, j0 = jt * 128;
    const float* aorg = (it < 32) ? X + (size_t)i0 * 256 : Y + (size_t)(i0 - N_S) * 256;
    const float* borg = (jt < 32) ? X + (size_t)j0 * 256 : Y + (size_t)(j0 - N_S) * 256;
    const float* fA = featsR + (size_t)i0 * 64;
    const float* fB = featsR + (size_t)j0 * 64;

    double epd = (double)ep[0];
    double eps = 1.0 / (1.0 + exp(-epd));
    double sqv = (double)sq[0], spv = (double)sph[0];
    float cf = (float)(LOG2E / (spv * spv));            // feature exponent scale
    float twoco = (float)(2.0 * LOG2E / (sqv * sqv));   // org dot exponent scale
    float epsv = (float)eps, ome = (float)(1.0 - eps);

    // prefetch buffer (one K=64 block: 8 float4 per thread)
    float4 R[8];
    auto loadregs = [&](const float* Ab, const float* Bb, int stride, int koff) {
#pragma unroll
        for (int step = 0; step < 2; ++step) {
            int rr = step * 64 + (tid >> 3), g8 = tid & 7;
            const float* pa = Ab + (size_t)rr * stride + koff + g8 * 8;
            const float* pb = Bb + (size_t)rr * stride + koff + g8 * 8;
            R[step * 4 + 0] = *(const float4*)pa;
            R[step * 4 + 1] = *(const float4*)(pa + 4);
            R[step * 4 + 2] = *(const float4*)pb;
            R[step * 4 + 3] = *(const float4*)(pb + 4);
        }
    };

    uint4* Ahi = (uint4*)smem;
    uint4* Alo = Ahi + 1024;
    uint4* Bhi = Ahi + 2048;
    uint4* Blo = Ahi + 3072;

    auto stage = [&]() {
#pragma unroll
        for (int step = 0; step < 2; ++step) {
            int rr = step * 64 + (tid >> 3), g8 = tid & 7;
            int pg = rr * 8 + (g8 ^ (rr & 7));          // XOR swizzle, conflict-free b128
            uint4 hi, lo;
            cvt_split(R[step * 4 + 0], R[step * 4 + 1], &hi, &lo);
            Ahi[pg] = hi; Alo[pg] = lo;
            cvt_split(R[step * 4 + 2], R[step * 4 + 3], &hi, &lo);
            Bhi[pg] = hi; Blo[pg] = lo;
        }
    };

    int rs0 = wr2 * 64 + (lane & 31), rs1 = rs0 + 32;
    int cs = wc4 * 32 + (lane & 31);

    auto mfma_block = [&](v16f& a0, v16f& a1) {
#pragma unroll
        for (int ks = 0; ks < 4; ++ks) {
            int g = ks * 2 + (lane >> 5);
            v8h ah0 = ldfrag(Ahi, rs0, g), ah1 = ldfrag(Ahi, rs1, g);
            v8h al0 = ldfrag(Alo, rs0, g), al1 = ldfrag(Alo, rs1, g);
            v8h bh = ldfrag(Bhi, cs, g), bl = ldfrag(Blo, cs, g);
            a0 = __builtin_amdgcn_mfma_f32_32x32x16_f16(al0, bh, a0, 0, 0, 0);
            a0 = __builtin_amdgcn_mfma_f32_32x32x16_f16(ah0, bl, a0, 0, 0, 0);
            a0 = __builtin_amdgcn_mfma_f32_32x32x16_f16(ah0, bh, a0, 0, 0, 0);
            a1 = __builtin_amdgcn_mfma_f32_32x32x16_f16(al1, bh, a1, 0, 0, 0);
            a1 = __builtin_amdgcn_mfma_f32_32x32x16_f16(ah1, bl, a1, 0, 0, 0);
            a1 = __builtin_amdgcn_mfma_f32_32x32x16_f16(ah1, bh, a1, 0, 0, 0);
        }
    };

    v16f accG0{}, accG1{}, accF0{}, accF1{};

    // ---- K-loop: 4 org K-blocks (K=256) then 1 feature K-block (K=64) ----
    loadregs(aorg, borg, 256, 0);
    for (int kb = 0; kb < 4; ++kb) {
        stage();
        __syncthreads();            // vmcnt naturally 0 here (R consumed)
        if (kb < 3) loadregs(aorg, borg, 256, (kb + 1) * 64);
        else        loadregs(fA, fB, 64, 0);
        __builtin_amdgcn_s_setprio(1);
        mfma_block(accG0, accG1);
        __builtin_amdgcn_s_setprio(0);
        // raw barrier: ds_reads consumed by MFMAs (lgkm drained), no ds_writes
        // pending; keeps prefetch loads in flight across the barrier.
        __builtin_amdgcn_sched_barrier(0);
        __builtin_amdgcn_s_barrier();
        __builtin_amdgcn_sched_barrier(0);
    }
    stage();
    __syncthreads();
    __builtin_amdgcn_s_setprio(1);
    mfma_block(accF0, accF1);
    __builtin_amdgcn_s_setprio(0);
    __builtin_amdgcn_sched_barrier(0);
    __builtin_amdgcn_s_barrier();       // frag reads done before E2 overwrite
    __builtin_amdgcn_sched_barrier(0);

    // ---- epilogue: kernel values in-register, E2 LDS tile for row sums ----
    float* E2 = (float*)smem;

    double bsum = 0.0, trsum = 0.0;
    float colacc = 0.0f;
    int cl = wc4 * 32 + (lane & 31);
    float wb = wOrg[j0 + cl];
    float nbF = normF[j0 + cl];

    auto evalacc = [&](const v16f& aG, const v16f& aF, int rbase) {
        float4 wa4[4], na4[4];
#pragma unroll
        for (int q = 0; q < 4; ++q) {
            int rb = i0 + rbase + 4 * (lane >> 5) + 8 * q;
            wa4[q] = *(const float4*)&wOrg[rb];
            na4[q] = *(const float4*)&normF[rb];
        }
#pragma unroll
        for (int reg = 0; reg < 16; ++reg) {
            int rl = rbase + 4 * (lane >> 5) + (reg & 3) + 8 * (reg >> 2);
            float wa = ((const float*)&wa4[reg >> 2])[reg & 3];
            float naA = ((const float*)&na4[reg >> 2])[reg & 3];
            float dfeat = fmaxf(naA + nbF - 2.0f * aF[reg], 0.0f);
            float e2v = exp2f(-dfeat * cf);
            float kv = wa * wb * exp2f(aG[reg] * twoco) * (ome * e2v + epsv);
            if (isDiag && rl == cl) kv = 0.0f;
            if (isTrace && cl == rl) trsum += (double)kv;
            bsum += (double)kv;
            colacc += kv;
            E2[rl * 128 + cl] = kv;
        }
    };
    evalacc(accG0, accF0, wr2 * 64);
    evalacc(accG1, accF1, wr2 * 64 + 32);
    __syncthreads();

    // row sums: 4 threads per row, rotated start to spread banks
    {
        int row = tid >> 2, q = tid & 3;
        float s = 0.0f;
#pragma unroll
        for (int c = 0; c < 8; ++c) {
            int cc = (c + row) & 7;
            float4 v = *(const float4*)&E2[row * 128 + q * 32 + cc * 4];
            s += v.x + v.y + v.z + v.w;
        }
        s += __shfl_xor(s, 1);
        s += __shfl_xor(s, 2);
        if (q == 0) atomicAdd(&D8[i0 + row], sgn * s);
    }

    // column sums (skip for diagonal tiles: rows already cover both triangles)
    if (!isDiag) {
        atomicAdd(&D8[j0 + cl], sgn * colacc);
    }

    // block reduce bsum (+ trace): wave shuffle then 8-way LDS
#pragma unroll
    for (int off = 32; off > 0; off >>= 1) bsum += __shfl_down(bsum, off);
    if (isTrace) {
#pragma unroll
        for (int off = 32; off > 0; off >>= 1) trsum += __shfl_down(trsum, off);
    }
    __syncthreads();               // E2 reads done; reuse smem as dred
    double* dred = (double*)smem;
    if (lane == 0) { dred[w] = bsum; dred[8 + w] = trsum; }
    __syncthreads();
    if (tid == 0) {
        double wgt = (sameHalf && !isDiag) ? 2.0 : 1.0;
        double t0 = 0.0, t1 = 0.0;
#pragma unroll
        for (int q = 0; q < 8; ++q) { t0 += dred[q]; t1 += dred[8 + q]; }
        atomicAdd(&S[region], wgt * t0);
        if (isTrace) atomicAdd(&S[3], t1);
    }
}

// ---------------- final scalar assembly ----------------
__global__ __launch_bounds__(256)
void final_kernel(const float* __restrict__ D8, const double* __restrict__ S,
                  float* __restrict__ out)
{
    __shared__ double buf[512];
    int tid = threadIdx.x;
    double sD = 0, sD2 = 0;
    for (int i = tid; i < 4096; i += 256) {
        double d = (double)D8[i] + (double)D8[i + 4096];
        sD += d; sD2 += d * d;
    }
    buf[tid] = sD; buf[256 + tid] = sD2;
    __syncthreads();
    for (int s = 128; s > 0; s >>= 1) {
        if (tid < s) { buf[tid] += buf[tid + s]; buf[256 + tid] += buf[256 + tid + s]; }
        __syncthreads();
    }
    if (tid == 0) {
        double n = (double)N_S, D = n * (n - 1.0);
        double xx = S[0] / D, yy = S[1] / D, xy = (S[2] - S[3]) / D;
        double mmd2 = xx - 2.0 * xy + yy;
        double sumd = buf[0], sumd2 = buf[256];
        double sumh = 2.0 * n + sumd;                    // hs_i = 2 + delta_i
        double sumhs2 = 4.0 * n + 4.0 * sumd + sumd2;
        double n3 = n * n * n, n4 = n3 * n;
        double var = 4.0 / n3 * sumhs2 - 4.0 / n4 * sumh * sumh + 1e-8;
        out[0] = (float)mmd2;
        out[1] = (float)var;
    }
}

extern "C" void kernel_launch(void* const* d_in, const int* in_sizes, int n_in,
                              void* d_out, int out_size, void* d_ws, size_t ws_size,
                              hipStream_t stream)
{
    const float* X   = (const float*)d_in[0];
    const float* Y   = (const float*)d_in[1];
    const float* W1  = (const float*)d_in[2];
    const float* b1  = (const float*)d_in[3];
    const float* W2  = (const float*)d_in[4];
    const float* b2  = (const float*)d_in[5];
    const float* W3  = (const float*)d_in[6];
    const float* b3  = (const float*)d_in[7];
    const float* W4  = (const float*)d_in[8];
    const float* b4  = (const float*)d_in[9];
    const float* ep  = (const float*)d_in[10];
    const float* sq  = (const float*)d_in[11];
    const float* sph = (const float*)d_in[12];
    float* out = (float*)d_out;

    char* ws = (char*)d_ws;
    float*  featsR = (float*)ws;                      // 8192*64*4 = 2097152
    float*  wOrg   = (float*)(ws + 2097152);          // 32768
    float*  normF  = (float*)(ws + 2129920);          // 32768
    float*  D8     = (float*)(ws + 2162688);          // 32768
    double* S      = (double*)(ws + 2195456);         // 32 (Sxx, Syy, Sxy, trace)

    hipMemsetAsync(D8, 0, 32768 + 32, stream);

    mlp_kernel<<<256, 256, 0, stream>>>(X, Y, W1, b1, W2, b2, W3, b3, W4, b4,
                                        sq, featsR, normF, wOrg);

    pair_kernel<<<2080, 512, 0, stream>>>(X, Y, featsR, normF, wOrg,
                                          ep, sq, sph, D8, S);

    final_kernel<<<1, 256, 0, stream>>>(D8, S, out);
}

// Round 5
// 209.184 us; speedup vs baseline: 1.3842x; 1.0923x over previous
//
#include <hip/hip_runtime.h>
#include <math.h>

// DeepMMD, round 7: joint symmetric 8192x8192 pass, 128x128 tiles (2080 blocks).
//  - mlp packs PK[8192][10][8] uint4: per-row f16 hi/lo MFMA fragments for both
//    org (8 K=32 sub-blocks) and features (2 sub-blocks), in LDS-read order.
//  - pair K-loop: 10 K=32 sub-blocks, double-buffered 2x32KiB LDS, staged with
//    global_load_lds dwordx4 (linear dest, per-lane XOR-swizzled source) and
//    counted s_waitcnt vmcnt(4): next sub-block's loads in flight across MFMA.
//    Zero ds_writes / zero cvt VALU in the hot loop (was 25% of LDS traffic,
//    35% of VALU).
//  - kernel eval: d = na + nb - 2*dot via MFMA norm-trick (validated r6);
//    org dot fp16 hi/lo 3-product on v_mfma_f32_32x32x16_f16.
//  - reductions: row/col sums -> fp32 atomics on D8[8192]; S* fp64 atomics.

#define N_S 4096
#define LOG2E 1.4426950408889634

typedef _Float16 v8h __attribute__((ext_vector_type(8)));
typedef float v16f __attribute__((ext_vector_type(16)));

union U16 { uint4 u; v8h h; };

__device__ __forceinline__ void pack_hilo(const float* fv, uint4* hi, uint4* lo) {
    U16 H, L;
#pragma unroll
    for (int u = 0; u < 8; ++u) {
        _Float16 h = (_Float16)fv[u];
        H.h[u] = h;
        L.h[u] = (_Float16)(fv[u] - (float)h);
    }
    *hi = H.u; *lo = L.u;
}

__device__ __forceinline__ void gload16(const void* g, void* lds) {
    __builtin_amdgcn_global_load_lds(
        (const __attribute__((address_space(1))) unsigned int*)g,
        (__attribute__((address_space(3))) unsigned int*)lds, 16, 0, 0);
}

// ---------------- MLP (fp64 internals), 8-way k-split ----------------
// -> PK[8192][10][8] uint4 (org sub 0..7, feat sub 8..9), normF[8192], wOrg[8192]
__global__ __launch_bounds__(256)
void mlp_kernel(const float* __restrict__ X, const float* __restrict__ Y,
                const float* __restrict__ W1, const float* __restrict__ b1,
                const float* __restrict__ W2, const float* __restrict__ b2,
                const float* __restrict__ W3, const float* __restrict__ b3,
                const float* __restrict__ W4, const float* __restrict__ b4,
                const float* __restrict__ sq,
                uint4* __restrict__ PK, float* __restrict__ normF,
                float* __restrict__ wOrg)
{
    __shared__ double sW1[8 * 330];
    __shared__ double sW2[100], sW3[100], sW4[500];
    __shared__ double sb1[10], sb2[10], sb3[10], sb4[50];
    int tid = threadIdx.x;
    {
        int kg = tid >> 5, kl = tid & 31;
#pragma unroll
        for (int j = 0; j < 10; ++j)
            sW1[kg * 330 + kl * 10 + j] = (double)W1[tid * 10 + j];
    }
    for (int i = tid; i < 100; i += 256) { sW2[i] = (double)W2[i]; sW3[i] = (double)W3[i]; }
    for (int i = tid; i < 500; i += 256) sW4[i] = (double)W4[i];
    if (tid < 10) { sb1[tid] = (double)b1[tid]; sb2[tid] = (double)b2[tid]; sb3[tid] = (double)b3[tid]; }
    if (tid < 50) sb4[tid] = (double)b4[tid];
    __syncthreads();

    int gt = blockIdx.x * 256 + tid;
    int r = gt >> 3, g = gt & 7;
    const float* xr = (r < N_S) ? (X + (size_t)r * 256) : (Y + (size_t)(r - N_S) * 256);
    const float* xrg = xr + g * 32;
    const double* w1g = sW1 + g * 330;

    float xl[32];
    double z[10];
#pragma unroll
    for (int j = 0; j < 10; ++j) z[j] = 0.0;
    double nrm = 0.0;
    for (int k4 = 0; k4 < 32; k4 += 4) {
        float4 xv4 = *(const float4*)(xrg + k4);
        xl[k4] = xv4.x; xl[k4 + 1] = xv4.y; xl[k4 + 2] = xv4.z; xl[k4 + 3] = xv4.w;
        double xv[4] = {(double)xv4.x, (double)xv4.y, (double)xv4.z, (double)xv4.w};
#pragma unroll
        for (int u = 0; u < 4; ++u) {
            nrm += xv[u] * xv[u];
#pragma unroll
            for (int j = 0; j < 10; ++j) z[j] += xv[u] * w1g[(k4 + u) * 10 + j];
        }
    }
    // pack org sub-block g: 4 k-groups, hi/lo
    {
        size_t base = ((size_t)r * 10 + g) * 8;
#pragma unroll
        for (int u = 0; u < 4; ++u) {
            uint4 hi, lo;
            pack_hilo(&xl[u * 8], &hi, &lo);
            PK[base + u] = hi;
            PK[base + 4 + u] = lo;
        }
    }

#pragma unroll
    for (int off = 1; off < 8; off <<= 1) {
        nrm += __shfl_xor(nrm, off);
#pragma unroll
        for (int j = 0; j < 10; ++j) z[j] += __shfl_xor(z[j], off);
    }
#pragma unroll
    for (int j = 0; j < 10; ++j) z[j] += sb1[j];
#pragma unroll
    for (int j = 0; j < 10; ++j) z[j] = fmax(z[j], 0.0) + log1p(exp(-fabs(z[j])));

    double z2[10];
#pragma unroll
    for (int j = 0; j < 10; ++j) z2[j] = sb2[j];
#pragma unroll
    for (int k = 0; k < 10; ++k)
#pragma unroll
        for (int j = 0; j < 10; ++j) z2[j] += z[k] * sW2[k * 10 + j];
#pragma unroll
    for (int j = 0; j < 10; ++j) z2[j] = fmax(z2[j], 0.0) + log1p(exp(-fabs(z2[j])));

    double z3[10];
#pragma unroll
    for (int j = 0; j < 10; ++j) z3[j] = sb3[j];
#pragma unroll
    for (int k = 0; k < 10; ++k)
#pragma unroll
        for (int j = 0; j < 10; ++j) z3[j] += z2[k] * sW3[k * 10 + j];
#pragma unroll
    for (int j = 0; j < 10; ++j) z3[j] = fmax(z3[j], 0.0) + log1p(exp(-fabs(z3[j])));

    // all 8 lanes compute all 50 f values (identical fp64); lane g keeps j in [8g,8g+8)
    double nf = 0.0;
    float ff[8];
#pragma unroll
    for (int u = 0; u < 8; ++u) ff[u] = 0.0f;
#pragma unroll
    for (int j = 0; j < 50; ++j) {
        double f = sb4[j];
#pragma unroll
        for (int k = 0; k < 10; ++k) f += z3[k] * sW4[k * 50 + j];
        nf += f * f;
        if ((j >> 3) == g) ff[j & 7] = (float)f;
    }
    {
        uint4 hi, lo;
        pack_hilo(ff, &hi, &lo);
        size_t fb = ((size_t)r * 10 + 8 + (g >> 2)) * 8 + (g & 3);
        PK[fb] = hi;
        PK[fb + 4] = lo;
    }

    if (g == 0) {
        double sqv = (double)sq[0];
        double co = LOG2E / (sqv * sqv);
        wOrg[r] = (float)exp2(-nrm * co);
    }
    if (g == 1) normF[r] = (float)nf;
}

// ---------------- helpers ----------------
__device__ __forceinline__ v8h ldfrag(const uint4* buf, int s, int g) {
    U16 t; t.u = buf[s * 8 + (g ^ (s & 7))];
    return t.h;
}

// ---------------- joint pairwise pass (512 threads / 8 waves) ----------------
__global__ __launch_bounds__(512, 2)
void pair_kernel(const uint4* __restrict__ PK, const float* __restrict__ normF,
                 const float* __restrict__ wOrg,
                 const float* __restrict__ ep, const float* __restrict__ sq,
                 const float* __restrict__ sph,
                 float* __restrict__ D8, double* __restrict__ S)
{
    // LDS: K-loop: dbuf half hb at smem+hb*32768: A[128][8]u4 (16K) + B (16K)
    //      epilogue: E2[128][128] f32 = 65536; dred 16 f64 (overlaid)
    __shared__ __align__(16) char smem[65536];

    int tid = threadIdx.x;
    int lane = tid & 63, w = tid >> 6;
    int wr2 = w >> 2, wc4 = w & 3;          // wave grid: 2 row-halves x 4 col-quarters

    // upper-triangle tile decode
    int L = blockIdx.x, it = 0, span = 64;
    while (L >= span) { L -= span; --span; ++it; }
    int jt = it + L;

    bool sameHalf = (jt < 32) || (it >= 32);
    bool isDiag = (it == jt);
    bool isTrace = (jt == it + 32);
    int region = (jt < 32) ? 0 : ((it >= 32) ? 1 : 2);
    float sgn = sameHalf ? 1.0f : -1.0f;
    int i0 = it * 128, j0 = jt * 128;

    // stage sub-block t into buffer half hb: linear LDS dest, per-lane
    // XOR-swizzled global source (4 global_load_lds_dwordx4 per thread)
    auto stage = [&](int t, int hb) {
        char* Ab = smem + hb * 32768;
        char* Bb = Ab + 16384;
#pragma unroll
        for (int i = 0; i < 2; ++i) {
            int u = i * 512 + tid;
            int rr = u >> 3, hg = (u & 7) ^ (rr & 7);
            const uint4* ga = &PK[((size_t)(i0 + rr) * 10 + t) * 8 + hg];
            const uint4* gb = &PK[((size_t)(j0 + rr) * 10 + t) * 8 + hg];
            char* la = Ab + (i * 512 + (w << 6)) * 16;   // wave-uniform base
            char* lb = Bb + (i * 512 + (w << 6)) * 16;
            gload16(ga, la);
            gload16(gb, lb);
        }
    };

    int rs0 = wr2 * 64 + (lane & 31), rs1 = rs0 + 32;
    int cs = wc4 * 32 + (lane & 31);

    auto mfma_block = [&](int hb, v16f& a0, v16f& a1) {
        const uint4* Ab = (const uint4*)(smem + hb * 32768);
        const uint4* Bb = (const uint4*)(smem + hb * 32768 + 16384);
#pragma unroll
        for (int ks = 0; ks < 2; ++ks) {
            int gl = ks * 2 + (lane >> 5);
            v8h ah0 = ldfrag(Ab, rs0, gl), ah1 = ldfrag(Ab, rs1, gl);
            v8h al0 = ldfrag(Ab, rs0, 4 + gl), al1 = ldfrag(Ab, rs1, 4 + gl);
            v8h bh = ldfrag(Bb, cs, gl), bl = ldfrag(Bb, cs, 4 + gl);
            a0 = __builtin_amdgcn_mfma_f32_32x32x16_f16(al0, bh, a0, 0, 0, 0);
            a0 = __builtin_amdgcn_mfma_f32_32x32x16_f16(ah0, bl, a0, 0, 0, 0);
            a0 = __builtin_amdgcn_mfma_f32_32x32x16_f16(ah0, bh, a0, 0, 0, 0);
            a1 = __builtin_amdgcn_mfma_f32_32x32x16_f16(al1, bh, a1, 0, 0, 0);
            a1 = __builtin_amdgcn_mfma_f32_32x32x16_f16(ah1, bl, a1, 0, 0, 0);
            a1 = __builtin_amdgcn_mfma_f32_32x32x16_f16(ah1, bh, a1, 0, 0, 0);
        }
    };

    v16f accG0{}, accG1{}, accF0{}, accF1{};

    // ---- K-loop: 8 org + 2 feat sub-blocks (K=32 each), 2-deep pipeline ----
    stage(0, 0);
#pragma unroll
    for (int t = 0; t < 10; ++t) {
        int hb = t & 1;
        if (t < 9) {
            stage(t + 1, hb ^ 1);      // dest half last read at t-1 (barrier-protected)
            asm volatile("s_waitcnt vmcnt(4)" ::: "memory");   // own t-loads landed
        } else {
            asm volatile("s_waitcnt vmcnt(0)" ::: "memory");
        }
        __builtin_amdgcn_s_barrier();  // all waves' t-loads landed
        __builtin_amdgcn_s_setprio(1);
        if (t < 8) mfma_block(hb, accG0, accG1);
        else       mfma_block(hb, accF0, accF1);
        __builtin_amdgcn_s_setprio(0);
        // raw barrier: ds_reads consumed by MFMAs; keeps t+1 loads in flight
        __builtin_amdgcn_sched_barrier(0);
        __builtin_amdgcn_s_barrier();
        __builtin_amdgcn_sched_barrier(0);
    }

    // scalar params (loaded only now so vmcnt in the K-loop counted staging only)
    double epd = (double)ep[0];
    double eps = 1.0 / (1.0 + exp(-epd));
    double sqv = (double)sq[0], spv = (double)sph[0];
    float cf = (float)(LOG2E / (spv * spv));            // feature exponent scale
    float twoco = (float)(2.0 * LOG2E / (sqv * sqv));   // org dot exponent scale
    float epsv = (float)eps, ome = (float)(1.0 - eps);

    // ---- epilogue: kernel values in-register, E2 LDS tile for row sums ----
    float* E2 = (float*)smem;

    double bsum = 0.0, trsum = 0.0;
    float colacc = 0.0f;
    int cl = wc4 * 32 + (lane & 31);
    float wb = wOrg[j0 + cl];
    float nbF = normF[j0 + cl];

    auto evalacc = [&](const v16f& aG, const v16f& aF, int rbase) {
        float4 wa4[4], na4[4];
#pragma unroll
        for (int q = 0; q < 4; ++q) {
            int rb = i0 + rbase + 4 * (lane >> 5) + 8 * q;
            wa4[q] = *(const float4*)&wOrg[rb];
            na4[q] = *(const float4*)&normF[rb];
        }
#pragma unroll
        for (int reg = 0; reg < 16; ++reg) {
            int rl = rbase + 4 * (lane >> 5) + (reg & 3) + 8 * (reg >> 2);
            float wa = ((const float*)&wa4[reg >> 2])[reg & 3];
            float naA = ((const float*)&na4[reg >> 2])[reg & 3];
            float dfeat = fmaxf(naA + nbF - 2.0f * aF[reg], 0.0f);
            float e2v = exp2f(-dfeat * cf);
            float kv = wa * wb * exp2f(aG[reg] * twoco) * (ome * e2v + epsv);
            if (isDiag && rl == cl) kv = 0.0f;
            if (isTrace && cl == rl) trsum += (double)kv;
            bsum += (double)kv;
            colacc += kv;
            E2[rl * 128 + cl] = kv;
        }
    };
    evalacc(accG0, accF0, wr2 * 64);
    evalacc(accG1, accF1, wr2 * 64 + 32);
    __syncthreads();

    // row sums: 4 threads per row, rotated start to spread banks
    {
        int row = tid >> 2, q = tid & 3;
        float s = 0.0f;
#pragma unroll
        for (int c = 0; c < 8; ++c) {
            int cc = (c + row) & 7;
            float4 v = *(const float4*)&E2[row * 128 + q * 32 + cc * 4];
            s += v.x + v.y + v.z + v.w;
        }
        s += __shfl_xor(s, 1);
        s += __shfl_xor(s, 2);
        if (q == 0) atomicAdd(&D8[i0 + row], sgn * s);
    }

    // column sums (skip for diagonal tiles: rows already cover both triangles)
    if (!isDiag) {
        atomicAdd(&D8[j0 + cl], sgn * colacc);
    }

    // block reduce bsum (+ trace): wave shuffle then 8-way LDS
#pragma unroll
    for (int off = 32; off > 0; off >>= 1) bsum += __shfl_down(bsum, off);
    if (isTrace) {
#pragma unroll
        for (int off = 32; off > 0; off >>= 1) trsum += __shfl_down(trsum, off);
    }
    __syncthreads();               // E2 reads done; reuse smem as dred
    double* dred = (double*)smem;
    if (lane == 0) { dred[w] = bsum; dred[8 + w] = trsum; }
    __syncthreads();
    if (tid == 0) {
        double wgt = (sameHalf && !isDiag) ? 2.0 : 1.0;
        double t0 = 0.0, t1 = 0.0;
#pragma unroll
        for (int q = 0; q < 8; ++q) { t0 += dred[q]; t1 += dred[8 + q]; }
        atomicAdd(&S[region], wgt * t0);
        if (isTrace) atomicAdd(&S[3], t1);
    }
}

// ---------------- final scalar assembly ----------------
__global__ __launch_bounds__(256)
void final_kernel(const float* __restrict__ D8, const double* __restrict__ S,
                  float* __restrict__ out)
{
    __shared__ double buf[512];
    int tid = threadIdx.x;
    double sD = 0, sD2 = 0;
    for (int i = tid; i < 4096; i += 256) {
        double d = (double)D8[i] + (double)D8[i + 4096];
        sD += d; sD2 += d * d;
    }
    buf[tid] = sD; buf[256 + tid] = sD2;
    __syncthreads();
    for (int s = 128; s > 0; s >>= 1) {
        if (tid < s) { buf[tid] += buf[tid + s]; buf[256 + tid] += buf[256 + tid + s]; }
        __syncthreads();
    }
    if (tid == 0) {
        double n = (double)N_S, D = n * (n - 1.0);
        double xx = S[0] / D, yy = S[1] / D, xy = (S[2] - S[3]) / D;
        double mmd2 = xx - 2.0 * xy + yy;
        double sumd = buf[0], sumd2 = buf[256];
        double sumh = 2.0 * n + sumd;                    // hs_i = 2 + delta_i
        double sumhs2 = 4.0 * n + 4.0 * sumd + sumd2;
        double n3 = n * n * n, n4 = n3 * n;
        double var = 4.0 / n3 * sumhs2 - 4.0 / n4 * sumh * sumh + 1e-8;
        out[0] = (float)mmd2;
        out[1] = (float)var;
    }
}

extern "C" void kernel_launch(void* const* d_in, const int* in_sizes, int n_in,
                              void* d_out, int out_size, void* d_ws, size_t ws_size,
                              hipStream_t stream)
{
    const float* X   = (const float*)d_in[0];
    const float* Y   = (const float*)d_in[1];
    const float* W1  = (const float*)d_in[2];
    const float* b1  = (const float*)d_in[3];
    const float* W2  = (const float*)d_in[4];
    const float* b2  = (const float*)d_in[5];
    const float* W3  = (const float*)d_in[6];
    const float* b3  = (const float*)d_in[7];
    const float* W4  = (const float*)d_in[8];
    const float* b4  = (const float*)d_in[9];
    const float* ep  = (const float*)d_in[10];
    const float* sq  = (const float*)d_in[11];
    const float* sph = (const float*)d_in[12];
    float* out = (float*)d_out;

    char* ws = (char*)d_ws;
    uint4*  PK    = (uint4*)ws;                       // 8192*10*8*16 = 10485760
    float*  wOrg  = (float*)(ws + 10485760);          // 32768
    float*  normF = (float*)(ws + 10518528);          // 32768
    float*  D8    = (float*)(ws + 10551296);          // 32768
    double* S     = (double*)(ws + 10584064);         // 32 (Sxx, Syy, Sxy, trace)

    hipMemsetAsync(D8, 0, 32768 + 32, stream);

    mlp_kernel<<<256, 256, 0, stream>>>(X, Y, W1, b1, W2, b2, W3, b3, W4, b4,
                                        sq, PK, normF, wOrg);

    pair_kernel<<<2080, 512, 0, stream>>>(PK, normF, wOrg, ep, sq, sph, D8, S);

    final_kernel<<<1, 256, 0, stream>>>(D8, S, out);
}

// Round 6
// 205.757 us; speedup vs baseline: 1.4072x; 1.0167x over previous
//
#include <hip/hip_runtime.h>
#include <math.h>

// DeepMMD, round 8: joint symmetric 8192x8192 pass, 128x128 tiles (2080 blocks).
//  - K-loop now ONE barrier per iteration: [vmcnt(0); s_barrier; stage(t+1);
//    MFMA(t)]. Barrier proves (a) all waves' t-loads landed (each vmcnt'd own
//    loads pre-barrier) and (b) all waves done MFMA(t-1) before stage(t+1)
//    overwrites its buffer (stage post-barrier). 20 -> 11 barriers.
//  - XCD-chunked swizzle (2080 = 8*260, bijective): contiguous tile chunks per
//    XCD -> A-panel re-reads become same-XCD L2 hits -> lower staging latency.
//  - closed-form upper-triangle decode (was ~64-iter serial scalar loop);
//    stage(0) issued immediately after decode.
//  - D8/S zeroing folded into mlp_kernel (memset dispatch removed).
//  - kernel eval unchanged: d = na + nb - 2*dot MFMA norm-trick, org dot fp16
//    hi/lo 3-product on v_mfma_f32_32x32x16_f16 (validated r6/r7).

#define N_S 4096
#define LOG2E 1.4426950408889634

typedef _Float16 v8h __attribute__((ext_vector_type(8)));
typedef float v16f __attribute__((ext_vector_type(16)));

union U16 { uint4 u; v8h h; };

__device__ __forceinline__ void pack_hilo(const float* fv, uint4* hi, uint4* lo) {
    U16 H, L;
#pragma unroll
    for (int u = 0; u < 8; ++u) {
        _Float16 h = (_Float16)fv[u];
        H.h[u] = h;
        L.h[u] = (_Float16)(fv[u] - (float)h);
    }
    *hi = H.u; *lo = L.u;
}

__device__ __forceinline__ void gload16(const void* g, void* lds) {
    __builtin_amdgcn_global_load_lds(
        (const __attribute__((address_space(1))) unsigned int*)g,
        (__attribute__((address_space(3))) unsigned int*)lds, 16, 0, 0);
}

// ---------------- MLP (fp64 internals), 8-way k-split ----------------
// -> PK[8192][10][8] uint4 (org sub 0..7, feat sub 8..9), normF[8192], wOrg[8192]
// also zeroes D8[8192] and S[4] (replaces memset dispatch)
__global__ __launch_bounds__(256)
void mlp_kernel(const float* __restrict__ X, const float* __restrict__ Y,
                const float* __restrict__ W1, const float* __restrict__ b1,
                const float* __restrict__ W2, const float* __restrict__ b2,
                const float* __restrict__ W3, const float* __restrict__ b3,
                const float* __restrict__ W4, const float* __restrict__ b4,
                const float* __restrict__ sq,
                uint4* __restrict__ PK, float* __restrict__ normF,
                float* __restrict__ wOrg,
                float* __restrict__ D8, double* __restrict__ S)
{
    __shared__ double sW1[8 * 330];
    __shared__ double sW2[100], sW3[100], sW4[500];
    __shared__ double sb1[10], sb2[10], sb3[10], sb4[50];
    int tid = threadIdx.x;
    int gt = blockIdx.x * 256 + tid;

    // workspace zeroing (replaces hipMemsetAsync)
    if (gt < 8192) D8[gt] = 0.0f;
    else if (gt < 8196) S[gt - 8192] = 0.0;

    {
        int kg = tid >> 5, kl = tid & 31;
#pragma unroll
        for (int j = 0; j < 10; ++j)
            sW1[kg * 330 + kl * 10 + j] = (double)W1[tid * 10 + j];
    }
    for (int i = tid; i < 100; i += 256) { sW2[i] = (double)W2[i]; sW3[i] = (double)W3[i]; }
    for (int i = tid; i < 500; i += 256) sW4[i] = (double)W4[i];
    if (tid < 10) { sb1[tid] = (double)b1[tid]; sb2[tid] = (double)b2[tid]; sb3[tid] = (double)b3[tid]; }
    if (tid < 50) sb4[tid] = (double)b4[tid];
    __syncthreads();

    int r = gt >> 3, g = gt & 7;
    const float* xr = (r < N_S) ? (X + (size_t)r * 256) : (Y + (size_t)(r - N_S) * 256);
    const float* xrg = xr + g * 32;
    const double* w1g = sW1 + g * 330;

    float xl[32];
    double z[10];
#pragma unroll
    for (int j = 0; j < 10; ++j) z[j] = 0.0;
    double nrm = 0.0;
    for (int k4 = 0; k4 < 32; k4 += 4) {
        float4 xv4 = *(const float4*)(xrg + k4);
        xl[k4] = xv4.x; xl[k4 + 1] = xv4.y; xl[k4 + 2] = xv4.z; xl[k4 + 3] = xv4.w;
        double xv[4] = {(double)xv4.x, (double)xv4.y, (double)xv4.z, (double)xv4.w};
#pragma unroll
        for (int u = 0; u < 4; ++u) {
            nrm += xv[u] * xv[u];
#pragma unroll
            for (int j = 0; j < 10; ++j) z[j] += xv[u] * w1g[(k4 + u) * 10 + j];
        }
    }
    // pack org sub-block g: 4 k-groups, hi/lo
    {
        size_t base = ((size_t)r * 10 + g) * 8;
#pragma unroll
        for (int u = 0; u < 4; ++u) {
            uint4 hi, lo;
            pack_hilo(&xl[u * 8], &hi, &lo);
            PK[base + u] = hi;
            PK[base + 4 + u] = lo;
        }
    }

#pragma unroll
    for (int off = 1; off < 8; off <<= 1) {
        nrm += __shfl_xor(nrm, off);
#pragma unroll
        for (int j = 0; j < 10; ++j) z[j] += __shfl_xor(z[j], off);
    }
#pragma unroll
    for (int j = 0; j < 10; ++j) z[j] += sb1[j];
#pragma unroll
    for (int j = 0; j < 10; ++j) z[j] = fmax(z[j], 0.0) + log1p(exp(-fabs(z[j])));

    double z2[10];
#pragma unroll
    for (int j = 0; j < 10; ++j) z2[j] = sb2[j];
#pragma unroll
    for (int k = 0; k < 10; ++k)
#pragma unroll
        for (int j = 0; j < 10; ++j) z2[j] += z[k] * sW2[k * 10 + j];
#pragma unroll
    for (int j = 0; j < 10; ++j) z2[j] = fmax(z2[j], 0.0) + log1p(exp(-fabs(z2[j])));

    double z3[10];
#pragma unroll
    for (int j = 0; j < 10; ++j) z3[j] = sb3[j];
#pragma unroll
    for (int k = 0; k < 10; ++k)
#pragma unroll
        for (int j = 0; j < 10; ++j) z3[j] += z2[k] * sW3[k * 10 + j];
#pragma unroll
    for (int j = 0; j < 10; ++j) z3[j] = fmax(z3[j], 0.0) + log1p(exp(-fabs(z3[j])));

    // all 8 lanes compute all 50 f values (identical fp64); lane g keeps j in [8g,8g+8)
    double nf = 0.0;
    float ff[8];
#pragma unroll
    for (int u = 0; u < 8; ++u) ff[u] = 0.0f;
#pragma unroll
    for (int j = 0; j < 50; ++j) {
        double f = sb4[j];
#pragma unroll
        for (int k = 0; k < 10; ++k) f += z3[k] * sW4[k * 50 + j];
        nf += f * f;
        if ((j >> 3) == g) ff[j & 7] = (float)f;
    }
    {
        uint4 hi, lo;
        pack_hilo(ff, &hi, &lo);
        size_t fb = ((size_t)r * 10 + 8 + (g >> 2)) * 8 + (g & 3);
        PK[fb] = hi;
        PK[fb + 4] = lo;
    }

    if (g == 0) {
        double sqv = (double)sq[0];
        double co = LOG2E / (sqv * sqv);
        wOrg[r] = (float)exp2(-nrm * co);
    }
    if (g == 1) normF[r] = (float)nf;
}

// ---------------- helpers ----------------
__device__ __forceinline__ v8h ldfrag(const uint4* buf, int s, int g) {
    U16 t; t.u = buf[s * 8 + (g ^ (s & 7))];
    return t.h;
}

// ---------------- joint pairwise pass (512 threads / 8 waves) ----------------
__global__ __launch_bounds__(512, 4)
void pair_kernel(const uint4* __restrict__ PK, const float* __restrict__ normF,
                 const float* __restrict__ wOrg,
                 const float* __restrict__ ep, const float* __restrict__ sq,
                 const float* __restrict__ sph,
                 float* __restrict__ D8, double* __restrict__ S)
{
    // LDS: K-loop: dbuf half hb at smem+hb*32768: A[128][8]u4 (16K) + B (16K)
    //      epilogue: E2[128][128] f32 = 65536; dred 16 f64 (overlaid)
    __shared__ __align__(16) char smem[65536];

    int tid = threadIdx.x;
    int lane = tid & 63, w = tid >> 6;
    int wr2 = w >> 2, wc4 = w & 3;          // wave grid: 2 row-halves x 4 col-quarters

    // XCD-chunked swizzle (2080 = 8 * 260, bijective) + closed-form triangle decode
    int orig = blockIdx.x;
    int L = (orig & 7) * 260 + (orig >> 3);
    int it = (int)((129.0 - sqrt(16641.0 - 8.0 * (double)L)) * 0.5);
    while (it * (129 - it) / 2 > L) --it;
    while ((it + 1) * (128 - it) / 2 <= L) ++it;     // (it+1)*(129-(it+1))/2
    int jt = it + (L - it * (129 - it) / 2);
    int i0 = it * 128, j0 = jt * 128;

    // stage sub-block t into buffer half hb: linear LDS dest, per-lane
    // XOR-swizzled global source (4 global_load_lds_dwordx4 per thread)
    auto stage = [&](int t, int hb) {
        char* Ab = smem + hb * 32768;
        char* Bb = Ab + 16384;
#pragma unroll
        for (int i = 0; i < 2; ++i) {
            int u = i * 512 + tid;
            int rr = u >> 3, hg = (u & 7) ^ (rr & 7);
            const uint4* ga = &PK[((size_t)(i0 + rr) * 10 + t) * 8 + hg];
            const uint4* gb = &PK[((size_t)(j0 + rr) * 10 + t) * 8 + hg];
            char* la = Ab + (i * 512 + (w << 6)) * 16;   // wave-uniform base
            char* lb = Bb + (i * 512 + (w << 6)) * 16;
            gload16(ga, la);
            gload16(gb, lb);
        }
    };

    stage(0, 0);        // first loads fly while scalar setup below executes

    bool sameHalf = (jt < 32) || (it >= 32);
    bool isDiag = (it == jt);
    bool isTrace = (jt == it + 32);
    int region = (jt < 32) ? 0 : ((it >= 32) ? 1 : 2);
    float sgn = sameHalf ? 1.0f : -1.0f;

    int rs0 = wr2 * 64 + (lane & 31), rs1 = rs0 + 32;
    int cs = wc4 * 32 + (lane & 31);

    auto mfma_block = [&](int hb, v16f& a0, v16f& a1) {
        const uint4* Ab = (const uint4*)(smem + hb * 32768);
        const uint4* Bb = (const uint4*)(smem + hb * 32768 + 16384);
#pragma unroll
        for (int ks = 0; ks < 2; ++ks) {
            int gl = ks * 2 + (lane >> 5);
            v8h ah0 = ldfrag(Ab, rs0, gl), ah1 = ldfrag(Ab, rs1, gl);
            v8h al0 = ldfrag(Ab, rs0, 4 + gl), al1 = ldfrag(Ab, rs1, 4 + gl);
            v8h bh = ldfrag(Bb, cs, gl), bl = ldfrag(Bb, cs, 4 + gl);
            a0 = __builtin_amdgcn_mfma_f32_32x32x16_f16(al0, bh, a0, 0, 0, 0);
            a0 = __builtin_amdgcn_mfma_f32_32x32x16_f16(ah0, bl, a0, 0, 0, 0);
            a0 = __builtin_amdgcn_mfma_f32_32x32x16_f16(ah0, bh, a0, 0, 0, 0);
            a1 = __builtin_amdgcn_mfma_f32_32x32x16_f16(al1, bh, a1, 0, 0, 0);
            a1 = __builtin_amdgcn_mfma_f32_32x32x16_f16(ah1, bl, a1, 0, 0, 0);
            a1 = __builtin_amdgcn_mfma_f32_32x32x16_f16(ah1, bh, a1, 0, 0, 0);
        }
    };

    v16f accG0{}, accG1{}, accF0{}, accF1{};

    // ---- K-loop: 8 org + 2 feat sub-blocks (K=32 each), ONE barrier/iter ----
    // body t: [vmcnt(0) own t-loads; barrier (=> all waves' t-loads landed AND
    // all waves done MFMA(t-1) on hb^1); stage(t+1) into hb^1; MFMA(t) on hb]
#pragma unroll
    for (int t = 0; t < 10; ++t) {
        int hb = t & 1;
        asm volatile("s_waitcnt vmcnt(0)" ::: "memory");
        __builtin_amdgcn_sched_barrier(0);
        __builtin_amdgcn_s_barrier();
        __builtin_amdgcn_sched_barrier(0);
        if (t < 9) stage(t + 1, hb ^ 1);
        __builtin_amdgcn_s_setprio(1);
        if (t < 8) mfma_block(hb, accG0, accG1);
        else       mfma_block(hb, accF0, accF1);
        __builtin_amdgcn_s_setprio(0);
    }
    __syncthreads();    // all waves' ds_reads done before E2 overwrites buffers

    // scalar params (loaded only now so vmcnt in the K-loop counted staging only)
    double epd = (double)ep[0];
    double eps = 1.0 / (1.0 + exp(-epd));
    double sqv = (double)sq[0], spv = (double)sph[0];
    float cf = (float)(LOG2E / (spv * spv));            // feature exponent scale
    float twoco = (float)(2.0 * LOG2E / (sqv * sqv));   // org dot exponent scale
    float epsv = (float)eps, ome = (float)(1.0 - eps);

    // ---- epilogue: kernel values in-register, E2 LDS tile for row sums ----
    float* E2 = (float*)smem;

    double bsum = 0.0, trsum = 0.0;
    float colacc = 0.0f;
    int cl = wc4 * 32 + (lane & 31);
    float wb = wOrg[j0 + cl];
    float nbF = normF[j0 + cl];

    auto evalacc = [&](const v16f& aG, const v16f& aF, int rbase) {
        float4 wa4[4], na4[4];
#pragma unroll
        for (int q = 0; q < 4; ++q) {
            int rb = i0 + rbase + 4 * (lane >> 5) + 8 * q;
            wa4[q] = *(const float4*)&wOrg[rb];
            na4[q] = *(const float4*)&normF[rb];
        }
#pragma unroll
        for (int reg = 0; reg < 16; ++reg) {
            int rl = rbase + 4 * (lane >> 5) + (reg & 3) + 8 * (reg >> 2);
            float wa = ((const float*)&wa4[reg >> 2])[reg & 3];
            float naA = ((const float*)&na4[reg >> 2])[reg & 3];
            float dfeat = fmaxf(naA + nbF - 2.0f * aF[reg], 0.0f);
            float e2v = exp2f(-dfeat * cf);
            float kv = wa * wb * exp2f(aG[reg] * twoco) * (ome * e2v + epsv);
            if (isDiag && rl == cl) kv = 0.0f;
            if (isTrace && cl == rl) trsum += (double)kv;
            bsum += (double)kv;
            colacc += kv;
            E2[rl * 128 + cl] = kv;
        }
    };
    evalacc(accG0, accF0, wr2 * 64);
    evalacc(accG1, accF1, wr2 * 64 + 32);
    __syncthreads();

    // row sums: 4 threads per row, rotated start to spread banks
    {
        int row = tid >> 2, q = tid & 3;
        float s = 0.0f;
#pragma unroll
        for (int c = 0; c < 8; ++c) {
            int cc = (c + row) & 7;
            float4 v = *(const float4*)&E2[row * 128 + q * 32 + cc * 4];
            s += v.x + v.y + v.z + v.w;
        }
        s += __shfl_xor(s, 1);
        s += __shfl_xor(s, 2);
        if (q == 0) atomicAdd(&D8[i0 + row], sgn * s);
    }

    // column sums (skip for diagonal tiles: rows already cover both triangles)
    if (!isDiag) {
        atomicAdd(&D8[j0 + cl], sgn * colacc);
    }

    // block reduce bsum (+ trace): wave shuffle then 8-way LDS
#pragma unroll
    for (int off = 32; off > 0; off >>= 1) bsum += __shfl_down(bsum, off);
    if (isTrace) {
#pragma unroll
        for (int off = 32; off > 0; off >>= 1) trsum += __shfl_down(trsum, off);
    }
    __syncthreads();               // E2 reads done; reuse smem as dred
    double* dred = (double*)smem;
    if (lane == 0) { dred[w] = bsum; dred[8 + w] = trsum; }
    __syncthreads();
    if (tid == 0) {
        double wgt = (sameHalf && !isDiag) ? 2.0 : 1.0;
        double t0 = 0.0, t1 = 0.0;
#pragma unroll
        for (int q = 0; q < 8; ++q) { t0 += dred[q]; t1 += dred[8 + q]; }
        atomicAdd(&S[region], wgt * t0);
        if (isTrace) atomicAdd(&S[3], t1);
    }
}

// ---------------- final scalar assembly ----------------
__global__ __launch_bounds__(256)
void final_kernel(const float* __restrict__ D8, const double* __restrict__ S,
                  float* __restrict__ out)
{
    __shared__ double buf[512];
    int tid = threadIdx.x;
    double sD = 0, sD2 = 0;
    for (int i = tid; i < 4096; i += 256) {
        double d = (double)D8[i] + (double)D8[i + 4096];
        sD += d; sD2 += d * d;
    }
    buf[tid] = sD; buf[256 + tid] = sD2;
    __syncthreads();
    for (int s = 128; s > 0; s >>= 1) {
        if (tid < s) { buf[tid] += buf[tid + s]; buf[256 + tid] += buf[256 + tid + s]; }
        __syncthreads();
    }
    if (tid == 0) {
        double n = (double)N_S, D = n * (n - 1.0);
        double xx = S[0] / D, yy = S[1] / D, xy = (S[2] - S[3]) / D;
        double mmd2 = xx - 2.0 * xy + yy;
        double sumd = buf[0], sumd2 = buf[256];
        double sumh = 2.0 * n + sumd;                    // hs_i = 2 + delta_i
        double sumhs2 = 4.0 * n + 4.0 * sumd + sumd2;
        double n3 = n * n * n, n4 = n3 * n;
        double var = 4.0 / n3 * sumhs2 - 4.0 / n4 * sumh * sumh + 1e-8;
        out[0] = (float)mmd2;
        out[1] = (float)var;
    }
}

extern "C" void kernel_launch(void* const* d_in, const int* in_sizes, int n_in,
                              void* d_out, int out_size, void* d_ws, size_t ws_size,
                              hipStream_t stream)
{
    const float* X   = (const float*)d_in[0];
    const float* Y   = (const float*)d_in[1];
    const float* W1  = (const float*)d_in[2];
    const float* b1  = (const float*)d_in[3];
    const float* W2  = (const float*)d_in[4];
    const float* b2  = (const float*)d_in[5];
    const float* W3  = (const float*)d_in[6];
    const float* b3  = (const float*)d_in[7];
    const float* W4  = (const float*)d_in[8];
    const float* b4  = (const float*)d_in[9];
    const float* ep  = (const float*)d_in[10];
    const float* sq  = (const float*)d_in[11];
    const float* sph = (const float*)d_in[12];
    float* out = (float*)d_out;

    char* ws = (char*)d_ws;
    uint4*  PK    = (uint4*)ws;                       // 8192*10*8*16 = 10485760
    float*  wOrg  = (float*)(ws + 10485760);          // 32768
    float*  normF = (float*)(ws + 10518528);          // 32768
    float*  D8    = (float*)(ws + 10551296);          // 32768
    double* S     = (double*)(ws + 10584064);         // 32 (Sxx, Syy, Sxy, trace)

    mlp_kernel<<<256, 256, 0, stream>>>(X, Y, W1, b1, W2, b2, W3, b3, W4, b4,
                                        sq, PK, normF, wOrg, D8, S);

    pair_kernel<<<2080, 512, 0, stream>>>(PK, normF, wOrg, ep, sq, sph, D8, S);

    final_kernel<<<1, 256, 0, stream>>>(D8, S, out);
}

// Round 7
// 185.964 us; speedup vs baseline: 1.5570x; 1.1064x over previous
//
#include <hip/hip_runtime.h>
#include <math.h>

// DeepMMD, round 9: joint symmetric 8192x8192 pass, 128x128 tiles (2080 blocks).
//  - org dot now PURE f16 single-product (lo term dropped): wOrg holds exact
//    fp64 norms, so only the cross-dot is f16-rounded -> do error ~0.02 on a
//    1/2048 exponent scale -> kv rel error ~1e-5, averaging to <1e-8 on outputs.
//    Cuts per-wave K-loop volume: MFMA 120->56, ds_read 120->72, staging -40%.
//  - feat dot keeps hi/lo 3-product (sigma_phi^2 = 0.005 is sensitive; r6-validated).
//  - PK layout: org subs 4 uint4/row (hi only, 4-slot XOR swizzle), feat 8 uint4.
//  - schedule unchanged from r8: one barrier/iter, vmcnt(0) own loads, XCD swizzle.

#define N_S 4096
#define LOG2E 1.4426950408889634

typedef _Float16 v8h __attribute__((ext_vector_type(8)));
typedef float v16f __attribute__((ext_vector_type(16)));

union U16 { uint4 u; v8h h; };

__device__ __forceinline__ void pack_hilo(const float* fv, uint4* hi, uint4* lo) {
    U16 H, L;
#pragma unroll
    for (int u = 0; u < 8; ++u) {
        _Float16 h = (_Float16)fv[u];
        H.h[u] = h;
        L.h[u] = (_Float16)(fv[u] - (float)h);
    }
    *hi = H.u; *lo = L.u;
}

__device__ __forceinline__ uint4 pack_hi(const float* fv) {
    U16 H;
#pragma unroll
    for (int u = 0; u < 8; ++u) H.h[u] = (_Float16)fv[u];
    return H.u;
}

__device__ __forceinline__ void gload16(const void* g, void* lds) {
    __builtin_amdgcn_global_load_lds(
        (const __attribute__((address_space(1))) unsigned int*)g,
        (__attribute__((address_space(3))) unsigned int*)lds, 16, 0, 0);
}

// ---------------- MLP (fp64 internals), 8-way k-split ----------------
// -> PK[8192][48] uint4: org subs t=0..7 at t*4 (4 hi u4, swizzle slot^(row&3)),
//    feat subs t=8,9 at 32+(t-8)*8 (4 hi + 4 lo, swizzle slot^(row&7)).
// also normF[8192], wOrg[8192]; zeroes D8[8192] and S[4].
__global__ __launch_bounds__(256)
void mlp_kernel(const float* __restrict__ X, const float* __restrict__ Y,
                const float* __restrict__ W1, const float* __restrict__ b1,
                const float* __restrict__ W2, const float* __restrict__ b2,
                const float* __restrict__ W3, const float* __restrict__ b3,
                const float* __restrict__ W4, const float* __restrict__ b4,
                const float* __restrict__ sq,
                uint4* __restrict__ PK, float* __restrict__ normF,
                float* __restrict__ wOrg,
                float* __restrict__ D8, double* __restrict__ S)
{
    __shared__ double sW1[8 * 330];
    __shared__ double sW2[100], sW3[100], sW4[500];
    __shared__ double sb1[10], sb2[10], sb3[10], sb4[50];
    int tid = threadIdx.x;
    int gt = blockIdx.x * 256 + tid;

    // workspace zeroing (replaces hipMemsetAsync)
    if (gt < 8192) D8[gt] = 0.0f;
    else if (gt < 8196) S[gt - 8192] = 0.0;

    {
        int kg = tid >> 5, kl = tid & 31;
#pragma unroll
        for (int j = 0; j < 10; ++j)
            sW1[kg * 330 + kl * 10 + j] = (double)W1[tid * 10 + j];
    }
    for (int i = tid; i < 100; i += 256) { sW2[i] = (double)W2[i]; sW3[i] = (double)W3[i]; }
    for (int i = tid; i < 500; i += 256) sW4[i] = (double)W4[i];
    if (tid < 10) { sb1[tid] = (double)b1[tid]; sb2[tid] = (double)b2[tid]; sb3[tid] = (double)b3[tid]; }
    if (tid < 50) sb4[tid] = (double)b4[tid];
    __syncthreads();

    int r = gt >> 3, g = gt & 7;
    const float* xr = (r < N_S) ? (X + (size_t)r * 256) : (Y + (size_t)(r - N_S) * 256);
    const float* xrg = xr + g * 32;
    const double* w1g = sW1 + g * 330;

    float xl[32];
    double z[10];
#pragma unroll
    for (int j = 0; j < 10; ++j) z[j] = 0.0;
    double nrm = 0.0;
    for (int k4 = 0; k4 < 32; k4 += 4) {
        float4 xv4 = *(const float4*)(xrg + k4);
        xl[k4] = xv4.x; xl[k4 + 1] = xv4.y; xl[k4 + 2] = xv4.z; xl[k4 + 3] = xv4.w;
        double xv[4] = {(double)xv4.x, (double)xv4.y, (double)xv4.z, (double)xv4.w};
#pragma unroll
        for (int u = 0; u < 4; ++u) {
            nrm += xv[u] * xv[u];
#pragma unroll
            for (int j = 0; j < 10; ++j) z[j] += xv[u] * w1g[(k4 + u) * 10 + j];
        }
    }
    // pack org sub-block g: 4 k-groups, hi only
    {
        size_t base = (size_t)r * 48 + g * 4;
#pragma unroll
        for (int u = 0; u < 4; ++u)
            PK[base + u] = pack_hi(&xl[u * 8]);
    }

#pragma unroll
    for (int off = 1; off < 8; off <<= 1) {
        nrm += __shfl_xor(nrm, off);
#pragma unroll
        for (int j = 0; j < 10; ++j) z[j] += __shfl_xor(z[j], off);
    }
#pragma unroll
    for (int j = 0; j < 10; ++j) z[j] += sb1[j];
#pragma unroll
    for (int j = 0; j < 10; ++j) z[j] = fmax(z[j], 0.0) + log1p(exp(-fabs(z[j])));

    double z2[10];
#pragma unroll
    for (int j = 0; j < 10; ++j) z2[j] = sb2[j];
#pragma unroll
    for (int k = 0; k < 10; ++k)
#pragma unroll
        for (int j = 0; j < 10; ++j) z2[j] += z[k] * sW2[k * 10 + j];
#pragma unroll
    for (int j = 0; j < 10; ++j) z2[j] = fmax(z2[j], 0.0) + log1p(exp(-fabs(z2[j])));

    double z3[10];
#pragma unroll
    for (int j = 0; j < 10; ++j) z3[j] = sb3[j];
#pragma unroll
    for (int k = 0; k < 10; ++k)
#pragma unroll
        for (int j = 0; j < 10; ++j) z3[j] += z2[k] * sW3[k * 10 + j];
#pragma unroll
    for (int j = 0; j < 10; ++j) z3[j] = fmax(z3[j], 0.0) + log1p(exp(-fabs(z3[j])));

    // all 8 lanes compute all 50 f values (identical fp64); lane g keeps j in [8g,8g+8)
    double nf = 0.0;
    float ff[8];
#pragma unroll
    for (int u = 0; u < 8; ++u) ff[u] = 0.0f;
#pragma unroll
    for (int j = 0; j < 50; ++j) {
        double f = sb4[j];
#pragma unroll
        for (int k = 0; k < 10; ++k) f += z3[k] * sW4[k * 50 + j];
        nf += f * f;
        if ((j >> 3) == g) ff[j & 7] = (float)f;
    }
    {
        uint4 hi, lo;
        pack_hilo(ff, &hi, &lo);
        size_t fb = (size_t)r * 48 + 32 + (g >> 2) * 8 + (g & 3);
        PK[fb] = hi;
        PK[fb + 4] = lo;
    }

    if (g == 0) {
        double sqv = (double)sq[0];
        double co = LOG2E / (sqv * sqv);
        wOrg[r] = (float)exp2(-nrm * co);
    }
    if (g == 1) normF[r] = (float)nf;
}

// ---------------- helpers ----------------
__device__ __forceinline__ v8h ldfrag8(const uint4* buf, int s, int g) {
    U16 t; t.u = buf[s * 8 + (g ^ (s & 7))];
    return t.h;
}
__device__ __forceinline__ v8h ldfrag4(const uint4* buf, int s, int g) {
    U16 t; t.u = buf[s * 4 + (g ^ (s & 3))];
    return t.h;
}

// ---------------- joint pairwise pass (512 threads / 8 waves) ----------------
__global__ __launch_bounds__(512, 4)
void pair_kernel(const uint4* __restrict__ PK, const float* __restrict__ normF,
                 const float* __restrict__ wOrg,
                 const float* __restrict__ ep, const float* __restrict__ sq,
                 const float* __restrict__ sph,
                 float* __restrict__ D8, double* __restrict__ S)
{
    // LDS: K-loop dbuf half hb at smem+hb*32768:
    //   org sub: A[128][4]u4 (8K) @0 + B (8K) @8192
    //   feat sub: A[128][8]u4 (16K) @0 + B (16K) @16384
    // epilogue: E2[128][128] f32 = 65536; dred 16 f64 (overlaid)
    __shared__ __align__(16) char smem[65536];

    int tid = threadIdx.x;
    int lane = tid & 63, w = tid >> 6;
    int wr2 = w >> 2, wc4 = w & 3;          // wave grid: 2 row-halves x 4 col-quarters

    // XCD-chunked swizzle (2080 = 8 * 260, bijective) + closed-form triangle decode
    int orig = blockIdx.x;
    int L = (orig & 7) * 260 + (orig >> 3);
    int it = (int)((129.0 - sqrt(16641.0 - 8.0 * (double)L)) * 0.5);
    while (it * (129 - it) / 2 > L) --it;
    while ((it + 1) * (128 - it) / 2 <= L) ++it;
    int jt = it + (L - it * (129 - it) / 2);
    int i0 = it * 128, j0 = jt * 128;

    // stage sub-block t into buffer half hb: linear LDS dest, per-lane
    // XOR-swizzled global source
    auto stage = [&](int t, int hb) {
        char* Ab = smem + hb * 32768;
        if (t < 8) {                 // org: 4 u4/row, 2 gloads per thread
            char* Bb = Ab + 8192;
            int rr = tid >> 2, slot = tid & 3, hg = slot ^ (rr & 3);
            const uint4* ga = &PK[(size_t)(i0 + rr) * 48 + t * 4 + hg];
            const uint4* gb = &PK[(size_t)(j0 + rr) * 48 + t * 4 + hg];
            char* la = Ab + (w << 10);      // wave-uniform base (64 lanes x 16B)
            char* lb = Bb + (w << 10);
            gload16(ga, la);
            gload16(gb, lb);
        } else {                     // feat: 8 u4/row, 4 gloads per thread
            char* Bb = Ab + 16384;
#pragma unroll
            for (int i = 0; i < 2; ++i) {
                int u = i * 512 + tid;
                int rr = u >> 3, hg = (u & 7) ^ (rr & 7);
                const uint4* ga = &PK[(size_t)(i0 + rr) * 48 + 32 + (t - 8) * 8 + hg];
                const uint4* gb = &PK[(size_t)(j0 + rr) * 48 + 32 + (t - 8) * 8 + hg];
                char* la = Ab + (i * 512 + (w << 6)) * 16;
                char* lb = Bb + (i * 512 + (w << 6)) * 16;
                gload16(ga, la);
                gload16(gb, lb);
            }
        }
    };

    stage(0, 0);        // first loads fly while scalar setup below executes

    bool sameHalf = (jt < 32) || (it >= 32);
    bool isDiag = (it == jt);
    bool isTrace = (jt == it + 32);
    int region = (jt < 32) ? 0 : ((it >= 32) ? 1 : 2);
    float sgn = sameHalf ? 1.0f : -1.0f;

    int rs0 = wr2 * 64 + (lane & 31), rs1 = rs0 + 32;
    int cs = wc4 * 32 + (lane & 31);

    // org: pure f16 single product (2 MFMA per ks)
    auto mfma_org = [&](int hb, v16f& a0, v16f& a1) {
        const uint4* Ab = (const uint4*)(smem + hb * 32768);
        const uint4* Bb = (const uint4*)(smem + hb * 32768 + 8192);
#pragma unroll
        for (int ks = 0; ks < 2; ++ks) {
            int gl = ks * 2 + (lane >> 5);
            v8h ah0 = ldfrag4(Ab, rs0, gl), ah1 = ldfrag4(Ab, rs1, gl);
            v8h bh = ldfrag4(Bb, cs, gl);
            a0 = __builtin_amdgcn_mfma_f32_32x32x16_f16(ah0, bh, a0, 0, 0, 0);
            a1 = __builtin_amdgcn_mfma_f32_32x32x16_f16(ah1, bh, a1, 0, 0, 0);
        }
    };
    // feat: hi/lo 3-product (6 MFMA per ks)
    auto mfma_feat = [&](int hb, v16f& a0, v16f& a1) {
        const uint4* Ab = (const uint4*)(smem + hb * 32768);
        const uint4* Bb = (const uint4*)(smem + hb * 32768 + 16384);
#pragma unroll
        for (int ks = 0; ks < 2; ++ks) {
            int gl = ks * 2 + (lane >> 5);
            v8h ah0 = ldfrag8(Ab, rs0, gl), ah1 = ldfrag8(Ab, rs1, gl);
            v8h al0 = ldfrag8(Ab, rs0, 4 + gl), al1 = ldfrag8(Ab, rs1, 4 + gl);
            v8h bh = ldfrag8(Bb, cs, gl), bl = ldfrag8(Bb, cs, 4 + gl);
            a0 = __builtin_amdgcn_mfma_f32_32x32x16_f16(al0, bh, a0, 0, 0, 0);
            a0 = __builtin_amdgcn_mfma_f32_32x32x16_f16(ah0, bl, a0, 0, 0, 0);
            a0 = __builtin_amdgcn_mfma_f32_32x32x16_f16(ah0, bh, a0, 0, 0, 0);
            a1 = __builtin_amdgcn_mfma_f32_32x32x16_f16(al1, bh, a1, 0, 0, 0);
            a1 = __builtin_amdgcn_mfma_f32_32x32x16_f16(ah1, bl, a1, 0, 0, 0);
            a1 = __builtin_amdgcn_mfma_f32_32x32x16_f16(ah1, bh, a1, 0, 0, 0);
        }
    };

    v16f accG0{}, accG1{}, accF0{}, accF1{};

    // ---- K-loop: 8 org + 2 feat sub-blocks (K=32 each), ONE barrier/iter ----
    // body t: [vmcnt(0) own t-loads; barrier (=> all waves' t-loads landed AND
    // all waves done MFMA(t-1) on hb^1); stage(t+1) into hb^1; MFMA(t) on hb]
#pragma unroll
    for (int t = 0; t < 10; ++t) {
        int hb = t & 1;
        asm volatile("s_waitcnt vmcnt(0)" ::: "memory");
        __builtin_amdgcn_sched_barrier(0);
        __builtin_amdgcn_s_barrier();
        __builtin_amdgcn_sched_barrier(0);
        if (t < 9) stage(t + 1, hb ^ 1);
        __builtin_amdgcn_s_setprio(1);
        if (t < 8) mfma_org(hb, accG0, accG1);
        else       mfma_feat(hb, accF0, accF1);
        __builtin_amdgcn_s_setprio(0);
    }
    __syncthreads();    // all waves' ds_reads done before E2 overwrites buffers

    // scalar params
    double epd = (double)ep[0];
    double eps = 1.0 / (1.0 + exp(-epd));
    double sqv = (double)sq[0], spv = (double)sph[0];
    float cf = (float)(LOG2E / (spv * spv));            // feature exponent scale
    float twoco = (float)(2.0 * LOG2E / (sqv * sqv));   // org dot exponent scale
    float epsv = (float)eps, ome = (float)(1.0 - eps);

    // ---- epilogue: kernel values in-register, E2 LDS tile for row sums ----
    float* E2 = (float*)smem;

    double bsum = 0.0, trsum = 0.0;
    float colacc = 0.0f;
    int cl = wc4 * 32 + (lane & 31);
    float wb = wOrg[j0 + cl];
    float nbF = normF[j0 + cl];

    auto evalacc = [&](const v16f& aG, const v16f& aF, int rbase) {
        float4 wa4[4], na4[4];
#pragma unroll
        for (int q = 0; q < 4; ++q) {
            int rb = i0 + rbase + 4 * (lane >> 5) + 8 * q;
            wa4[q] = *(const float4*)&wOrg[rb];
            na4[q] = *(const float4*)&normF[rb];
        }
#pragma unroll
        for (int reg = 0; reg < 16; ++reg) {
            int rl = rbase + 4 * (lane >> 5) + (reg & 3) + 8 * (reg >> 2);
            float wa = ((const float*)&wa4[reg >> 2])[reg & 3];
            float naA = ((const float*)&na4[reg >> 2])[reg & 3];
            float dfeat = fmaxf(naA + nbF - 2.0f * aF[reg], 0.0f);
            float e2v = exp2f(-dfeat * cf);
            float kv = wa * wb * exp2f(aG[reg] * twoco) * (ome * e2v + epsv);
            if (isDiag && rl == cl) kv = 0.0f;
            if (isTrace && cl == rl) trsum += (double)kv;
            bsum += (double)kv;
            colacc += kv;
            E2[rl * 128 + cl] = kv;
        }
    };
    evalacc(accG0, accF0, wr2 * 64);
    evalacc(accG1, accF1, wr2 * 64 + 32);
    __syncthreads();

    // row sums: 4 threads per row, rotated start to spread banks
    {
        int row = tid >> 2, q = tid & 3;
        float s = 0.0f;
#pragma unroll
        for (int c = 0; c < 8; ++c) {
            int cc = (c + row) & 7;
            float4 v = *(const float4*)&E2[row * 128 + q * 32 + cc * 4];
            s += v.x + v.y + v.z + v.w;
        }
        s += __shfl_xor(s, 1);
        s += __shfl_xor(s, 2);
        if (q == 0) atomicAdd(&D8[i0 + row], sgn * s);
    }

    // column sums (skip for diagonal tiles: rows already cover both triangles)
    if (!isDiag) {
        atomicAdd(&D8[j0 + cl], sgn * colacc);
    }

    // block reduce bsum (+ trace): wave shuffle then 8-way LDS
#pragma unroll
    for (int off = 32; off > 0; off >>= 1) bsum += __shfl_down(bsum, off);
    if (isTrace) {
#pragma unroll
        for (int off = 32; off > 0; off >>= 1) trsum += __shfl_down(trsum, off);
    }
    __syncthreads();               // E2 reads done; reuse smem as dred
    double* dred = (double*)smem;
    if (lane == 0) { dred[w] = bsum; dred[8 + w] = trsum; }
    __syncthreads();
    if (tid == 0) {
        double wgt = (sameHalf && !isDiag) ? 2.0 : 1.0;
        double t0 = 0.0, t1 = 0.0;
#pragma unroll
        for (int q = 0; q < 8; ++q) { t0 += dred[q]; t1 += dred[8 + q]; }
        atomicAdd(&S[region], wgt * t0);
        if (isTrace) atomicAdd(&S[3], t1);
    }
}

// ---------------- final scalar assembly ----------------
__global__ __launch_bounds__(256)
void final_kernel(const float* __restrict__ D8, const double* __restrict__ S,
                  float* __restrict__ out)
{
    __shared__ double buf[512];
    int tid = threadIdx.x;
    double sD = 0, sD2 = 0;
    for (int i = tid; i < 4096; i += 256) {
        double d = (double)D8[i] + (double)D8[i + 4096];
        sD += d; sD2 += d * d;
    }
    buf[tid] = sD; buf[256 + tid] = sD2;
    __syncthreads();
    for (int s = 128; s > 0; s >>= 1) {
        if (tid < s) { buf[tid] += buf[tid + s]; buf[256 + tid] += buf[256 + tid + s]; }
        __syncthreads();
    }
    if (tid == 0) {
        double n = (double)N_S, D = n * (n - 1.0);
        double xx = S[0] / D, yy = S[1] / D, xy = (S[2] - S[3]) / D;
        double mmd2 = xx - 2.0 * xy + yy;
        double sumd = buf[0], sumd2 = buf[256];
        double sumh = 2.0 * n + sumd;                    // hs_i = 2 + delta_i
        double sumhs2 = 4.0 * n + 4.0 * sumd + sumd2;
        double n3 = n * n * n, n4 = n3 * n;
        double var = 4.0 / n3 * sumhs2 - 4.0 / n4 * sumh * sumh + 1e-8;
        out[0] = (float)mmd2;
        out[1] = (float)var;
    }
}

extern "C" void kernel_launch(void* const* d_in, const int* in_sizes, int n_in,
                              void* d_out, int out_size, void* d_ws, size_t ws_size,
                              hipStream_t stream)
{
    const float* X   = (const float*)d_in[0];
    const float* Y   = (const float*)d_in[1];
    const float* W1  = (const float*)d_in[2];
    const float* b1  = (const float*)d_in[3];
    const float* W2  = (const float*)d_in[4];
    const float* b2  = (const float*)d_in[5];
    const float* W3  = (const float*)d_in[6];
    const float* b3  = (const float*)d_in[7];
    const float* W4  = (const float*)d_in[8];
    const float* b4  = (const float*)d_in[9];
    const float* ep  = (const float*)d_in[10];
    const float* sq  = (const float*)d_in[11];
    const float* sph = (const float*)d_in[12];
    float* out = (float*)d_out;

    char* ws = (char*)d_ws;
    uint4*  PK    = (uint4*)ws;                       // 8192*48*16 = 6291456
    float*  wOrg  = (float*)(ws + 6291456);           // 32768
    float*  normF = (float*)(ws + 6324224);           // 32768
    float*  D8    = (float*)(ws + 6356992);           // 32768
    double* S     = (double*)(ws + 6389760);          // 32 (Sxx, Syy, Sxy, trace)

    mlp_kernel<<<256, 256, 0, stream>>>(X, Y, W1, b1, W2, b2, W3, b3, W4, b4,
                                        sq, PK, normF, wOrg, D8, S);

    pair_kernel<<<2080, 512, 0, stream>>>(PK, normF, wOrg, ep, sq, sph, D8, S);

    final_kernel<<<1, 256, 0, stream>>>(D8, S, out);
}